// Round 6
// baseline (5675.051 us; speedup 1.0000x reference)
//
#include <hip/hip_runtime.h>
#include <hip/hip_bf16.h>

using bf16 = __hip_bfloat16;

#define T_SEQ 4096
#define DWC 512

__device__ __forceinline__ float fin(float v) {
    return (v == v && fabsf(v) < 1e30f) ? v : 0.0f;
}
// flag-branched float load: f32=1 -> fp32 array, f32=0 -> bf16 array
__device__ __forceinline__ float ldf(const void* p, size_t i, int f32) {
    return f32 ? ((const float*)p)[i]
               : __bfloat162float(((const bf16*)p)[i]);
}

// ---------------------------------------------------------------- diagnostics
__global__ __launch_bounds__(256) void diag_kernel(bf16* __restrict__ out, int n, float v)
{
    int i = blockIdx.x * 256 + threadIdx.x;
    if (i < n) out[i] = __float2bfloat16(i == 0 ? v : 0.0f);
}
__global__ void canary_write(unsigned int* p) { if (threadIdx.x == 0) *p = 0x5EC7CAFEu; }
__global__ void canary_check(const unsigned int* p, bf16* out)
{
    if (threadIdx.x == 0 && *p != 0x5EC7CAFEu)
        for (int i = 0; i < 64; i++) out[i] = __float2bfloat16(7.77e36f);
}

// flags[0]=tok is64, flags[1]=bpe width{1,4,8}, flags[2]=wm width, flags[3]=seg is64,
// flags[4]=float width (1=fp32, 0=bf16). tok_emb row0 is zeroed => bytes 128..255
// are zero iff fp32 (row-0 tail), nonzero iff bf16 (they hold row 1).
__global__ __launch_bounds__(256) void detect_kernel(
    const int* __restrict__ tok, const unsigned char* __restrict__ bpe,
    const unsigned char* __restrict__ wm, const int* __restrict__ seg,
    const unsigned int* __restrict__ embw, int* __restrict__ flags)
{
    __shared__ int sh[5];
    int tid = threadIdx.x;
    if (tid < 5) sh[tid] = 0;
    __syncthreads();
    int bo = 0, bm = 0, wo = 0, wmid = 0;
    for (int i = tid; i < 16384; i += 256) {
        int odd = 2 * i + 1;
        if (bpe[odd]) bo = 1;
        if (wm[odd])  wo = 1;
        int mid = 8 * (i & 4095) + 4;
        if (bpe[mid]) bm = 1;
        if (wm[mid])  wmid = 1;
    }
    if (bo)   atomicOr(&sh[0], 1);
    if (bm)   atomicOr(&sh[1], 1);
    if (wo)   atomicOr(&sh[2], 1);
    if (wmid) atomicOr(&sh[3], 1);
    if (tid < 32 && embw[32 + tid] != 0u) atomicOr(&sh[4], 1);
    __syncthreads();
    if (tid == 0) {
        flags[0] = (tok[32767] != 0) ? 0 : 1;
        flags[1] = sh[0] ? 1 : (sh[1] ? 4 : 8);
        flags[2] = sh[2] ? 1 : (sh[3] ? 4 : 8);
        flags[3] = (seg[32767] != 0) ? 0 : 1;
        flags[4] = sh[4] ? 0 : 1;
    }
}

__global__ __launch_bounds__(256) void embed_kernel(
    const int* __restrict__ tok, const unsigned char* __restrict__ bpe,
    const unsigned char* __restrict__ wm, const void* __restrict__ emb,
    const int* __restrict__ flags, bf16* __restrict__ xe, int bt0)
{
    int i = blockIdx.x * 256 + threadIdx.x;
    int d = i & 63;
    int btl = i >> 6;
    int bt = bt0 + btl;
    int is64t = flags[0];
    int wb = flags[1], ww = flags[2];
    int f32 = flags[4];
    int t = is64t ? (int)((const long long*)tok)[bt] : tok[bt];
    t = min(max(t, 0), 263);
    float v = ldf(emb, (size_t)t * 64 + d, f32);
    if (bpe[(size_t)bt * wb]) v += ldf(emb, 4 * 64 + d, f32);
    if (wm[(size_t)bt * ww])  v += ldf(emb, 3 * 64 + d, f32);
    xe[i] = __float2bfloat16(fin(v));
}

template<int IC, bool RESID>
__global__ __launch_bounds__(256) void conv_gemm(
    const bf16* __restrict__ A, const void* __restrict__ W,
    const void* __restrict__ bias, const int* __restrict__ flags,
    bf16* __restrict__ Out)
{
    constexpr int K = 3 * IC;
    __shared__ float As[64][17];
    __shared__ float Bs[16][65];
    const int block_n = blockIdx.x * 64;
    const int block_m = blockIdx.y * 64;
    const int tid = threadIdx.x;
    const int tx = tid & 15, ty = tid >> 4;
    const int f32 = flags[4];
    float acc[4][4] = {};

    for (int k0 = 0; k0 < K; k0 += 16) {
        #pragma unroll
        for (int e = 0; e < 4; e++) {
            int idx = tid + e * 256;
            int r = idx >> 4, kk = idx & 15;
            int kg = k0 + kk;
            int tap = kg / IC;
            int c = kg - tap * IC;
            int gr = block_m + r;
            int t = gr & (T_SEQ - 1);
            int ts = t + tap - 1;
            float v = 0.0f;
            if (ts >= 0 && ts < T_SEQ)
                v = __bfloat162float(A[(size_t)(gr + tap - 1) * IC + c]);
            As[r][kk] = v;
        }
        #pragma unroll
        for (int e = 0; e < 4; e++) {
            int idx = tid + e * 256;
            int kk = idx >> 6, n = idx & 63;
            Bs[kk][n] = ldf(W, (size_t)(k0 + kk) * DWC + block_n + n, f32);
        }
        __syncthreads();
        #pragma unroll
        for (int kk = 0; kk < 16; kk++) {
            float a[4], b[4];
            #pragma unroll
            for (int i = 0; i < 4; i++) a[i] = As[ty * 4 + i][kk];
            #pragma unroll
            for (int j = 0; j < 4; j++) b[j] = Bs[kk][tx * 4 + j];
            #pragma unroll
            for (int i = 0; i < 4; i++)
                #pragma unroll
                for (int j = 0; j < 4; j++)
                    acc[i][j] += a[i] * b[j];
        }
        __syncthreads();
    }

    #pragma unroll
    for (int i = 0; i < 4; i++) {
        int r = block_m + ty * 4 + i;
        #pragma unroll
        for (int j = 0; j < 4; j++) {
            int n = block_n + tx * 4 + j;
            float v = acc[i][j] + ldf(bias, n, f32);
            if constexpr (RESID) v += __bfloat162float(A[(size_t)r * IC + n]);
            Out[(size_t)r * DWC + n] = __float2bfloat16(fin(fmaxf(v, 0.0f)));
        }
    }
}

// layer selects weights via ELEMENT offsets woff/boff (width-agnostic)
__global__ __launch_bounds__(256) void highway_gemm(
    const bf16* __restrict__ Y,
    const void* __restrict__ Wg, const void* __restrict__ bg,
    const void* __restrict__ Wh, const void* __restrict__ bh,
    const int* __restrict__ flags, bf16* __restrict__ Out,
    int woff, int boff)
{
    __shared__ float As[64][17];
    __shared__ float Bgs[16][65];
    __shared__ float Bhs[16][65];
    const int block_n = blockIdx.x * 64;
    const int block_m = blockIdx.y * 64;
    const int tid = threadIdx.x;
    const int tx = tid & 15, ty = tid >> 4;
    const int f32 = flags[4];
    float accg[4][4] = {};
    float acch[4][4] = {};

    for (int k0 = 0; k0 < DWC; k0 += 16) {
        #pragma unroll
        for (int e = 0; e < 4; e++) {
            int idx = tid + e * 256;
            int r = idx >> 4, kk = idx & 15;
            As[r][kk] = __bfloat162float(Y[(size_t)(block_m + r) * DWC + k0 + kk]);
        }
        #pragma unroll
        for (int e = 0; e < 4; e++) {
            int idx = tid + e * 256;
            int kk = idx >> 6, n = idx & 63;
            size_t wi = (size_t)woff + (size_t)(k0 + kk) * DWC + block_n + n;
            Bgs[kk][n] = ldf(Wg, wi, f32);
            Bhs[kk][n] = ldf(Wh, wi, f32);
        }
        __syncthreads();
        #pragma unroll
        for (int kk = 0; kk < 16; kk++) {
            float a[4], g[4], h[4];
            #pragma unroll
            for (int i = 0; i < 4; i++) a[i] = As[ty * 4 + i][kk];
            #pragma unroll
            for (int j = 0; j < 4; j++) { g[j] = Bgs[kk][tx * 4 + j]; h[j] = Bhs[kk][tx * 4 + j]; }
            #pragma unroll
            for (int i = 0; i < 4; i++)
                #pragma unroll
                for (int j = 0; j < 4; j++) {
                    accg[i][j] += a[i] * g[j];
                    acch[i][j] += a[i] * h[j];
                }
        }
        __syncthreads();
    }

    #pragma unroll
    for (int i = 0; i < 4; i++) {
        int r = block_m + ty * 4 + i;
        #pragma unroll
        for (int j = 0; j < 4; j++) {
            int n = block_n + tx * 4 + j;
            float gv = accg[i][j] + ldf(bg, (size_t)boff + n, f32);
            float hv = acch[i][j] + ldf(bh, (size_t)boff + n, f32);
            float g = 1.0f / (1.0f + expf(-gv));
            float h = fmaxf(hv, 0.0f);
            float y = __bfloat162float(Y[(size_t)r * DWC + n]);
            Out[(size_t)r * DWC + n] = __float2bfloat16(fin(g * h + (1.0f - g) * y));
        }
    }
}

// writes d_out at element offset oroff*DWC, dtype per flags[4]
__global__ __launch_bounds__(256) void proj_gemm(
    const bf16* __restrict__ A, const void* __restrict__ W,
    const void* __restrict__ bias, const int* __restrict__ flags,
    void* __restrict__ Out, int oroff)
{
    __shared__ float As[64][17];
    __shared__ float Bs[16][65];
    const int block_n = blockIdx.x * 64;
    const int block_m = blockIdx.y * 64;
    const int tid = threadIdx.x;
    const int tx = tid & 15, ty = tid >> 4;
    const int f32 = flags[4];
    float acc[4][4] = {};

    for (int k0 = 0; k0 < DWC; k0 += 16) {
        #pragma unroll
        for (int e = 0; e < 4; e++) {
            int idx = tid + e * 256;
            int r = idx >> 4, kk = idx & 15;
            As[r][kk] = __bfloat162float(A[(size_t)(block_m + r) * DWC + k0 + kk]);
        }
        #pragma unroll
        for (int e = 0; e < 4; e++) {
            int idx = tid + e * 256;
            int kk = idx >> 6, n = idx & 63;
            Bs[kk][n] = ldf(W, (size_t)(k0 + kk) * DWC + block_n + n, f32);
        }
        __syncthreads();
        #pragma unroll
        for (int kk = 0; kk < 16; kk++) {
            float a[4], b[4];
            #pragma unroll
            for (int i = 0; i < 4; i++) a[i] = As[ty * 4 + i][kk];
            #pragma unroll
            for (int j = 0; j < 4; j++) b[j] = Bs[kk][tx * 4 + j];
            #pragma unroll
            for (int i = 0; i < 4; i++)
                #pragma unroll
                for (int j = 0; j < 4; j++)
                    acc[i][j] += a[i] * b[j];
        }
        __syncthreads();
    }

    #pragma unroll
    for (int i = 0; i < 4; i++) {
        int r = block_m + ty * 4 + i;
        #pragma unroll
        for (int j = 0; j < 4; j++) {
            int n = block_n + tx * 4 + j;
            float v = fin(acc[i][j] + ldf(bias, n, f32));
            size_t oi = (size_t)(oroff + r) * DWC + n;
            if (f32) ((float*)Out)[oi] = v;
            else     ((bf16*)Out)[oi]  = __float2bfloat16(v);
        }
    }
}

__global__ __launch_bounds__(256) void bounds_kernel(
    const int* __restrict__ seg, const int* __restrict__ flags,
    int* __restrict__ wstart, int* __restrict__ wend, int bt0)
{
    int il = blockIdx.x * 256 + threadIdx.x;
    int ig = bt0 + il;
    int is64 = flags[3];
    const long long* seg64 = (const long long*)seg;
    int t = il & (T_SEQ - 1);
    int bl = il >> 12;
    int s  = (is64 ? (int)seg64[ig] : seg[ig]) & 1023;
    int sp = (t == 0)         ? -1 : ((is64 ? (int)seg64[ig - 1] : seg[ig - 1]) & 1023);
    int sn = (t == T_SEQ - 1) ? -1 : ((is64 ? (int)seg64[ig + 1] : seg[ig + 1]) & 1023);
    int bw = (bl << 10) + s;
    if (sp != s) wstart[bw] = t;
    if (sn != s) wend[bw] = t;
}

__global__ __launch_bounds__(512) void segmax_kernel(
    const bf16* __restrict__ Y, const int* __restrict__ wstart,
    const int* __restrict__ wend, bf16* __restrict__ Out)
{
    int bw = blockIdx.x;
    int d = threadIdx.x;
    int bl = bw >> 10;
    int s = wstart[bw], e = wend[bw];
    s = min(max(s, 0), T_SEQ - 1);
    e = min(max(e, s), T_SEQ - 1);
    float m = __bfloat162float(Y[(size_t)((bl << 12) + s) * DWC + d]);
    for (int t = s + 1; t <= e; ++t)
        m = fmaxf(m, __bfloat162float(Y[(size_t)((bl << 12) + t) * DWC + d]));
    Out[(size_t)bw * DWC + d] = __float2bfloat16(fin(m));
}

// ---------------------------------------------------------------- launch
extern "C" void kernel_launch(void* const* d_in, const int* in_sizes, int n_in,
                              void* d_out, int out_size, void* d_ws, size_t ws_size,
                              hipStream_t stream)
{
    static const int expect[19] = {32768, 32768, 32768, 32768, 16896,
                                   98304, 512, 524288, 1024, 524288, 1024,
                                   786432, 512, 524288, 1024, 524288, 1024,
                                   262144, 512};
    int bad = -1;
    if (n_in < 19) bad = 31;
    else for (int i = 0; i < 19; i++) if (in_sizes[i] != expect[i]) { bad = i; break; }
    if (bad >= 0) {
        diag_kernel<<<dim3((out_size + 255) / 256), dim3(256), 0, stream>>>(
            (bf16*)d_out, out_size, 1e35f * (float)(1 + bad));
        return;
    }

    const size_t unit = 8ull << 20;
    if (ws_size < unit) {
        float ws_mib = (float)((double)ws_size / 1048576.0);
        diag_kernel<<<dim3((out_size + 255) / 256), dim3(256), 0, stream>>>(
            (bf16*)d_out, out_size, 1e30f * (16.0f + ws_mib));
        return;
    }

    const int*  byte_tokens = (const int*)d_in[0];
    const unsigned char* bpe_mask = (const unsigned char*)d_in[1];
    const unsigned char* word_mask = (const unsigned char*)d_in[2];
    const int*  seg_ids     = (const int*)d_in[3];
    const void* tok_emb = d_in[4];
    const void* conv0_w = d_in[5],  *conv0_b = d_in[6];
    const void* hw0_wg  = d_in[7],  *hw0_bg  = d_in[8];
    const void* hw0_wh  = d_in[9],  *hw0_bh  = d_in[10];
    const void* conv1_w = d_in[11], *conv1_b = d_in[12];
    const void* hw1_wg  = d_in[13], *hw1_bg  = d_in[14];
    const void* hw1_wh  = d_in[15], *hw1_bh  = d_in[16];
    const void* proj_w  = d_in[17], *proj_b  = d_in[18];

    char* ws = (char*)d_ws;
    int C = 8;
    while ((size_t)C * unit > ws_size) C >>= 1;

    unsigned int* canary = nullptr;
    if (ws_size >= (size_t)C * unit + 64)
        canary = (unsigned int*)(ws + (size_t)C * unit);
    if (canary) canary_write<<<dim3(1), dim3(64), 0, stream>>>(canary);

    const int WOFF = DWC * DWC;   // element offset of highway layer 1 weights
    const int BOFF = DWC;

    for (int b0 = 0; b0 < 8; b0 += C) {
        const int rows  = C * T_SEQ;
        const int words = C * 1024;
        bf16* bufA   = (bf16*)ws;
        bf16* bufB   = (bf16*)(ws + (size_t)C * (4u << 20));
        bf16* xe     = bufB;                      // dies when hw0a writes bufB
        int*  flags1 = (int*)bufA;                // dies when conv0 writes bufA
        bf16* segout = bufA;                      // valid after bufA dies post-hw1b
        int*  wstart = (int*)(ws + (size_t)C * (1u << 20));
        int*  wend   = wstart + words;
        int*  flags2 = wend + words;

        detect_kernel<<<dim3(1), dim3(256), 0, stream>>>(
            byte_tokens, bpe_mask, word_mask, seg_ids,
            (const unsigned int*)tok_emb, flags1);

        embed_kernel<<<dim3(rows * 64 / 256), dim3(256), 0, stream>>>(
            byte_tokens, bpe_mask, word_mask, tok_emb, flags1, xe, b0 * T_SEQ);

        conv_gemm<64, false><<<dim3(DWC / 64, rows / 64), dim3(256), 0, stream>>>(
            xe, conv0_w, conv0_b, flags1, bufA);

        highway_gemm<<<dim3(DWC / 64, rows / 64), dim3(256), 0, stream>>>(
            bufA, hw0_wg, hw0_bg, hw0_wh, hw0_bh, flags1, bufB, 0, 0);
        highway_gemm<<<dim3(DWC / 64, rows / 64), dim3(256), 0, stream>>>(
            bufB, hw0_wg, hw0_bg, hw0_wh, hw0_bh, flags1, bufA, WOFF, BOFF);

        conv_gemm<512, true><<<dim3(DWC / 64, rows / 64), dim3(256), 0, stream>>>(
            bufA, conv1_w, conv1_b, flags1, bufB);

        highway_gemm<<<dim3(DWC / 64, rows / 64), dim3(256), 0, stream>>>(
            bufB, hw1_wg, hw1_bg, hw1_wh, hw1_bh, flags1, bufA, 0, 0);
        highway_gemm<<<dim3(DWC / 64, rows / 64), dim3(256), 0, stream>>>(
            bufA, hw1_wg, hw1_bg, hw1_wh, hw1_bh, flags1, bufB, WOFF, BOFF);

        detect_kernel<<<dim3(1), dim3(256), 0, stream>>>(
            byte_tokens, bpe_mask, word_mask, seg_ids,
            (const unsigned int*)tok_emb, flags2);
        bounds_kernel<<<dim3(rows / 256), dim3(256), 0, stream>>>(
            seg_ids, flags2, wstart, wend, b0 * T_SEQ);

        segmax_kernel<<<dim3(words), dim3(512), 0, stream>>>(
            bufB, wstart, wend, segout);

        proj_gemm<<<dim3(DWC / 64, words / 64), dim3(256), 0, stream>>>(
            segout, proj_w, proj_b, flags2, d_out, b0 * 1024);
    }

    if (canary) canary_check<<<dim3(1), dim3(64), 0, stream>>>(canary, (bf16*)d_out);
}

// Round 7
// 704.254 us; speedup vs baseline: 8.0582x; 8.0582x over previous
//
#include <hip/hip_runtime.h>
#include <hip/hip_bf16.h>

using bf16 = __hip_bfloat16;
typedef __attribute__((ext_vector_type(8))) short s8v;   // 8 bf16 in 4 VGPRs
typedef __attribute__((ext_vector_type(4))) float f4v;   // mfma accumulator

#define T_SEQ 4096
#define DWC 512

__device__ __forceinline__ float fin(float v) {
    return (v == v && fabsf(v) < 1e30f) ? v : 0.0f;
}
__device__ __forceinline__ float ldf(const void* p, size_t i, int f32) {
    return f32 ? ((const float*)p)[i] : __bfloat162float(((const bf16*)p)[i]);
}
__device__ __forceinline__ float b2f(short s) {
    unsigned u = ((unsigned)(unsigned short)s) << 16;
    return __builtin_bit_cast(float, u);
}
__device__ __forceinline__ short f2b(float v) {
    bf16 b = __float2bfloat16(v);
    return __builtin_bit_cast(short, b);
}

// ---------------------------------------------------------------- diagnostics
__global__ __launch_bounds__(256) void diag_kernel(bf16* __restrict__ out, int n, float v)
{
    int i = blockIdx.x * 256 + threadIdx.x;
    if (i < n) out[i] = __float2bfloat16(i == 0 ? v : 0.0f);
}

// flags[0]=tok is64, flags[1]=bpe width{1,4,8}, flags[2]=wm width, flags[3]=seg is64,
// flags[4]=float width (1=fp32, 0=bf16)
__global__ __launch_bounds__(256) void detect_kernel(
    const int* __restrict__ tok, const unsigned char* __restrict__ bpe,
    const unsigned char* __restrict__ wm, const int* __restrict__ seg,
    const unsigned int* __restrict__ embw, int* __restrict__ flags)
{
    __shared__ int sh[5];
    int tid = threadIdx.x;
    if (tid < 5) sh[tid] = 0;
    __syncthreads();
    int bo = 0, bm = 0, wo = 0, wmid = 0;
    for (int i = tid; i < 16384; i += 256) {
        int odd = 2 * i + 1;
        if (bpe[odd]) bo = 1;
        if (wm[odd])  wo = 1;
        int mid = 8 * (i & 4095) + 4;
        if (bpe[mid]) bm = 1;
        if (wm[mid])  wmid = 1;
    }
    if (bo)   atomicOr(&sh[0], 1);
    if (bm)   atomicOr(&sh[1], 1);
    if (wo)   atomicOr(&sh[2], 1);
    if (wmid) atomicOr(&sh[3], 1);
    if (tid < 32 && embw[32 + tid] != 0u) atomicOr(&sh[4], 1);
    __syncthreads();
    if (tid == 0) {
        flags[0] = (tok[32767] != 0) ? 0 : 1;
        flags[1] = sh[0] ? 1 : (sh[1] ? 4 : 8);
        flags[2] = sh[2] ? 1 : (sh[3] ? 4 : 8);
        flags[3] = (seg[32767] != 0) ? 0 : 1;
        flags[4] = sh[4] ? 0 : 1;
    }
}

// ------------------------------------------------- weight convert + transpose
// WB element layout (shorts):
//  [0,98304)        c0wT  [512][192]   <- conv0_w [192][512]
//  [98304,98816)    c0b
//  [98816,623104)   hw0gT [2][512][512]<- hw0_wg [2][512][512] (transposed per layer)
//  [623104,624128)  hw0bg [2][512]
//  [624128,1148416) hw0hT
//  [1148416,1149440)hw0bh
//  [1149440,1935872)c1wT  [512][1536]  <- conv1_w [1536][512]
//  [1935872,1936384)c1b
//  [1936384,2460672)hw1gT
//  [2460672,2461696)hw1bg
//  [2461696,2985984)hw1hT
//  [2985984,2987008)hw1bh
//  [2987008,3249152)pwT   [512][512]
//  [3249152,3249664)pb
#define WB_TOTAL 3249664
__global__ __launch_bounds__(256) void convert_weights(
    const void* c0w, const void* c0b, const void* h0g, const void* h0bg,
    const void* h0h, const void* h0bh, const void* c1w, const void* c1b,
    const void* h1g, const void* h1bg, const void* h1h, const void* h1bh,
    const void* pw, const void* pb, const int* __restrict__ flags,
    short* __restrict__ WB)
{
    int f32 = flags[4];
    size_t i = (size_t)blockIdx.x * 256 + threadIdx.x;
    if (i >= WB_TOTAL) return;
    const void* src; size_t si;
    if (i < 98304)        { size_t n = i / 192, k = i % 192; src = c0w; si = k * 512 + n; }
    else if (i < 98816)   { src = c0b;  si = i - 98304; }
    else if (i < 623104)  { size_t o = i - 98816;  size_t l = o >> 18; o &= 262143;
                            size_t n = o >> 9, k = o & 511; src = h0g; si = (l << 18) + k * 512 + n; }
    else if (i < 624128)  { src = h0bg; si = i - 623104; }
    else if (i < 1148416) { size_t o = i - 624128; size_t l = o >> 18; o &= 262143;
                            size_t n = o >> 9, k = o & 511; src = h0h; si = (l << 18) + k * 512 + n; }
    else if (i < 1149440) { src = h0bh; si = i - 1148416; }
    else if (i < 1935872) { size_t o = i - 1149440; size_t n = o / 1536, k = o % 1536;
                            src = c1w; si = k * 512 + n; }
    else if (i < 1936384) { src = c1b;  si = i - 1935872; }
    else if (i < 2460672) { size_t o = i - 1936384; size_t l = o >> 18; o &= 262143;
                            size_t n = o >> 9, k = o & 511; src = h1g; si = (l << 18) + k * 512 + n; }
    else if (i < 2461696) { src = h1bg; si = i - 2460672; }
    else if (i < 2985984) { size_t o = i - 2461696; size_t l = o >> 18; o &= 262143;
                            size_t n = o >> 9, k = o & 511; src = h1h; si = (l << 18) + k * 512 + n; }
    else if (i < 2987008) { src = h1bh; si = i - 2985984; }
    else if (i < 3249152) { size_t o = i - 2987008; size_t n = o >> 9, k = o & 511;
                            src = pw; si = k * 512 + n; }
    else                  { src = pb;   si = i - 3249152; }
    WB[i] = f2b(ldf(src, si, f32));
}

// ---------------------------------------------------------------- embed
__global__ __launch_bounds__(256) void embed_kernel(
    const int* __restrict__ tok, const unsigned char* __restrict__ bpe,
    const unsigned char* __restrict__ wm, const void* __restrict__ emb,
    const int* __restrict__ flags, short* __restrict__ xe, int bt0)
{
    int i = blockIdx.x * 256 + threadIdx.x;
    int d = i & 63;
    int btl = i >> 6;
    int bt = bt0 + btl;
    int is64t = flags[0];
    int wb = flags[1], ww = flags[2];
    int f32 = flags[4];
    int t = is64t ? (int)((const long long*)tok)[bt] : tok[bt];
    t = min(max(t, 0), 263);
    float v = ldf(emb, (size_t)t * 64 + d, f32);
    if (bpe[(size_t)bt * wb]) v += ldf(emb, 4 * 64 + d, f32);
    if (wm[(size_t)bt * ww])  v += ldf(emb, 3 * 64 + d, f32);
    xe[i] = f2b(fin(v));
}

// ------------------------------------------------- MFMA conv-as-GEMM
// Out[r,n] = relu( sum_k Avirt[r,k] WT[n,k] + bias[n] (+A[r,n]) ), K=3*IC
// 128x128 tile, BK=32, 4 waves each 64x64 (4x4 mfma of 16x16x32).
template<int IC, bool RESID>
__global__ __launch_bounds__(256) void conv_mfma(
    const short* __restrict__ A, const short* __restrict__ WT,
    const short* __restrict__ bias, short* __restrict__ Out)
{
    constexpr int K = 3 * IC;
    __shared__ __align__(16) short As[128][40];
    __shared__ __align__(16) short Bs[128][40];
    const int bm = blockIdx.y * 128;
    const int bn = blockIdx.x * 128;
    const int tid = threadIdx.x;
    const int wave = tid >> 6, lane = tid & 63;
    const int wm = (wave >> 1) * 64, wn = (wave & 1) * 64;
    const int q = lane >> 4, ln16 = lane & 15;

    f4v acc[4][4] = {};

    for (int k0 = 0; k0 < K; k0 += 32) {
        const int tap = k0 / IC;
        const int c0 = k0 - tap * IC;
        #pragma unroll
        for (int it = 0; it < 2; it++) {
            int el = (tid + it * 256) * 8;
            int r = el >> 5, c = el & 31;
            int gr = bm + r;
            int t = gr & (T_SEQ - 1);
            int ts = t + tap - 1;
            uint4 va = make_uint4(0, 0, 0, 0);
            if (ts >= 0 && ts < T_SEQ)
                va = *(const uint4*)(A + (size_t)(gr + tap - 1) * IC + c0 + c);
            *(uint4*)(&As[r][c]) = va;
            *(uint4*)(&Bs[r][c]) = *(const uint4*)(WT + (size_t)(bn + r) * K + k0 + c);
        }
        __syncthreads();
        s8v af[4], bf[4];
        #pragma unroll
        for (int mi = 0; mi < 4; mi++) af[mi] = *(const s8v*)(&As[wm + mi * 16 + ln16][q * 8]);
        #pragma unroll
        for (int ni = 0; ni < 4; ni++) bf[ni] = *(const s8v*)(&Bs[wn + ni * 16 + ln16][q * 8]);
        #pragma unroll
        for (int mi = 0; mi < 4; mi++)
            #pragma unroll
            for (int ni = 0; ni < 4; ni++)
                acc[mi][ni] = __builtin_amdgcn_mfma_f32_16x16x32_bf16(
                    af[mi], bf[ni], acc[mi][ni], 0, 0, 0);
        __syncthreads();
    }

    #pragma unroll
    for (int mi = 0; mi < 4; mi++)
        #pragma unroll
        for (int ni = 0; ni < 4; ni++) {
            int col = bn + wn + ni * 16 + ln16;
            float bv = b2f(bias[col]);
            #pragma unroll
            for (int r = 0; r < 4; r++) {
                int row = bm + wm + mi * 16 + q * 4 + r;
                float v = acc[mi][ni][r] + bv;
                if constexpr (RESID) v += b2f(A[(size_t)row * IC + col]);
                Out[(size_t)row * DWC + col] = f2b(fin(fmaxf(v, 0.0f)));
            }
        }
}

// ------------------------------------------------- MFMA highway (dual GEMM)
__global__ __launch_bounds__(256) void highway_mfma(
    const short* __restrict__ Y, const short* __restrict__ WgT,
    const short* __restrict__ bg, const short* __restrict__ WhT,
    const short* __restrict__ bh, short* __restrict__ Out)
{
    __shared__ __align__(16) short As[128][40];
    __shared__ __align__(16) short Bg[128][40];
    __shared__ __align__(16) short Bh[128][40];
    const int bm = blockIdx.y * 128;
    const int bn = blockIdx.x * 128;
    const int tid = threadIdx.x;
    const int wave = tid >> 6, lane = tid & 63;
    const int wm = (wave >> 1) * 64, wn = (wave & 1) * 64;
    const int q = lane >> 4, ln16 = lane & 15;

    f4v accg[4][4] = {};
    f4v acch[4][4] = {};

    for (int k0 = 0; k0 < DWC; k0 += 32) {
        #pragma unroll
        for (int it = 0; it < 2; it++) {
            int el = (tid + it * 256) * 8;
            int r = el >> 5, c = el & 31;
            *(uint4*)(&As[r][c]) = *(const uint4*)(Y + (size_t)(bm + r) * DWC + k0 + c);
            *(uint4*)(&Bg[r][c]) = *(const uint4*)(WgT + (size_t)(bn + r) * DWC + k0 + c);
            *(uint4*)(&Bh[r][c]) = *(const uint4*)(WhT + (size_t)(bn + r) * DWC + k0 + c);
        }
        __syncthreads();
        s8v af[4], bgf[4], bhf[4];
        #pragma unroll
        for (int mi = 0; mi < 4; mi++) af[mi] = *(const s8v*)(&As[wm + mi * 16 + ln16][q * 8]);
        #pragma unroll
        for (int ni = 0; ni < 4; ni++) {
            bgf[ni] = *(const s8v*)(&Bg[wn + ni * 16 + ln16][q * 8]);
            bhf[ni] = *(const s8v*)(&Bh[wn + ni * 16 + ln16][q * 8]);
        }
        #pragma unroll
        for (int mi = 0; mi < 4; mi++)
            #pragma unroll
            for (int ni = 0; ni < 4; ni++) {
                accg[mi][ni] = __builtin_amdgcn_mfma_f32_16x16x32_bf16(
                    af[mi], bgf[ni], accg[mi][ni], 0, 0, 0);
                acch[mi][ni] = __builtin_amdgcn_mfma_f32_16x16x32_bf16(
                    af[mi], bhf[ni], acch[mi][ni], 0, 0, 0);
            }
        __syncthreads();
    }

    #pragma unroll
    for (int mi = 0; mi < 4; mi++)
        #pragma unroll
        for (int ni = 0; ni < 4; ni++) {
            int col = bn + wn + ni * 16 + ln16;
            float bgv = b2f(bg[col]);
            float bhv = b2f(bh[col]);
            #pragma unroll
            for (int r = 0; r < 4; r++) {
                int row = bm + wm + mi * 16 + q * 4 + r;
                float g = 1.0f / (1.0f + expf(-(accg[mi][ni][r] + bgv)));
                float h = fmaxf(acch[mi][ni][r] + bhv, 0.0f);
                float y = b2f(Y[(size_t)row * DWC + col]);
                Out[(size_t)row * DWC + col] = f2b(fin(g * h + (1.0f - g) * y));
            }
        }
}

// ------------------------------------------------- MFMA projection (fp32/bf16 out)
__global__ __launch_bounds__(256) void proj_mfma(
    const short* __restrict__ A, const short* __restrict__ WT,
    const short* __restrict__ bias, const int* __restrict__ flags,
    void* __restrict__ Out, int oroff)
{
    __shared__ __align__(16) short As[128][40];
    __shared__ __align__(16) short Bs[128][40];
    const int bm = blockIdx.y * 128;
    const int bn = blockIdx.x * 128;
    const int tid = threadIdx.x;
    const int wave = tid >> 6, lane = tid & 63;
    const int wm = (wave >> 1) * 64, wn = (wave & 1) * 64;
    const int q = lane >> 4, ln16 = lane & 15;
    const int f32 = flags[4];

    f4v acc[4][4] = {};

    for (int k0 = 0; k0 < DWC; k0 += 32) {
        #pragma unroll
        for (int it = 0; it < 2; it++) {
            int el = (tid + it * 256) * 8;
            int r = el >> 5, c = el & 31;
            *(uint4*)(&As[r][c]) = *(const uint4*)(A + (size_t)(bm + r) * DWC + k0 + c);
            *(uint4*)(&Bs[r][c]) = *(const uint4*)(WT + (size_t)(bn + r) * DWC + k0 + c);
        }
        __syncthreads();
        s8v af[4], bf[4];
        #pragma unroll
        for (int mi = 0; mi < 4; mi++) af[mi] = *(const s8v*)(&As[wm + mi * 16 + ln16][q * 8]);
        #pragma unroll
        for (int ni = 0; ni < 4; ni++) bf[ni] = *(const s8v*)(&Bs[wn + ni * 16 + ln16][q * 8]);
        #pragma unroll
        for (int mi = 0; mi < 4; mi++)
            #pragma unroll
            for (int ni = 0; ni < 4; ni++)
                acc[mi][ni] = __builtin_amdgcn_mfma_f32_16x16x32_bf16(
                    af[mi], bf[ni], acc[mi][ni], 0, 0, 0);
        __syncthreads();
    }

    #pragma unroll
    for (int mi = 0; mi < 4; mi++)
        #pragma unroll
        for (int ni = 0; ni < 4; ni++) {
            int col = bn + wn + ni * 16 + ln16;
            float bv = b2f(bias[col]);
            #pragma unroll
            for (int r = 0; r < 4; r++) {
                int row = bm + wm + mi * 16 + q * 4 + r;
                float v = fin(acc[mi][ni][r] + bv);
                size_t oi = (size_t)(oroff + row) * DWC + col;
                if (f32) ((float*)Out)[oi] = v;
                else     ((bf16*)Out)[oi] = __float2bfloat16(v);
            }
        }
}

// ---------------------------------------------------------------- bounds / segmax
__global__ __launch_bounds__(256) void bounds_kernel(
    const int* __restrict__ seg, const int* __restrict__ flags,
    int* __restrict__ wstart, int* __restrict__ wend, int bt0)
{
    int il = blockIdx.x * 256 + threadIdx.x;
    int ig = bt0 + il;
    int is64 = flags[3];
    const long long* seg64 = (const long long*)seg;
    int t = il & (T_SEQ - 1);
    int bl = il >> 12;
    int s  = (is64 ? (int)seg64[ig] : seg[ig]) & 1023;
    int sp = (t == 0)         ? -1 : ((is64 ? (int)seg64[ig - 1] : seg[ig - 1]) & 1023);
    int sn = (t == T_SEQ - 1) ? -1 : ((is64 ? (int)seg64[ig + 1] : seg[ig + 1]) & 1023);
    int bw = (bl << 10) + s;
    if (sp != s) wstart[bw] = t;
    if (sn != s) wend[bw] = t;
}

__global__ __launch_bounds__(512) void segmax_kernel(
    const short* __restrict__ Y, const int* __restrict__ wstart,
    const int* __restrict__ wend, short* __restrict__ Out)
{
    int bw = blockIdx.x;
    int d = threadIdx.x;
    int bl = bw >> 10;
    int s = wstart[bw], e = wend[bw];
    s = min(max(s, 0), T_SEQ - 1);
    e = min(max(e, s), T_SEQ - 1);
    float m = b2f(Y[(size_t)((bl << 12) + s) * DWC + d]);
    for (int t = s + 1; t <= e; ++t)
        m = fmaxf(m, b2f(Y[(size_t)((bl << 12) + t) * DWC + d]));
    Out[(size_t)bw * DWC + d] = f2b(fin(m));
}

// ---------------------------------------------------------------- launch
extern "C" void kernel_launch(void* const* d_in, const int* in_sizes, int n_in,
                              void* d_out, int out_size, void* d_ws, size_t ws_size,
                              hipStream_t stream)
{
    static const int expect[19] = {32768, 32768, 32768, 32768, 16896,
                                   98304, 512, 524288, 1024, 524288, 1024,
                                   786432, 512, 524288, 1024, 524288, 1024,
                                   262144, 512};
    int bad = -1;
    if (n_in < 19) bad = 31;
    else for (int i = 0; i < 19; i++) if (in_sizes[i] != expect[i]) { bad = i; break; }
    if (bad >= 0) {
        diag_kernel<<<dim3((out_size + 255) / 256), dim3(256), 0, stream>>>(
            (bf16*)d_out, out_size, 1e35f * (float)(1 + bad));
        return;
    }

    char* ws = (char*)d_ws;
    // ws layout: [0, 8MiB): WB weights (6.2MB used) + flags @ +6500352B
    //            [8MiB, ...): chunk region (xe | U | V | bounds); segout aliases U
    const size_t WBREG = 8ull << 20;
    short* WB    = (short*)ws;
    int*   flags = (int*)(ws + 6500352);
    const size_t perC = 8921088 + 8192 + 64;      // xe + U + V + bounds per batch
    int C = 8;
    while (C > 1 && WBREG + (size_t)C * perC > ws_size) C >>= 1;
    if (WBREG + (size_t)C * perC > ws_size) {
        float ws_mib = (float)((double)ws_size / 1048576.0);
        diag_kernel<<<dim3((out_size + 255) / 256), dim3(256), 0, stream>>>(
            (bf16*)d_out, out_size, 1e30f * (16.0f + ws_mib));
        return;
    }

    const int*  byte_tokens = (const int*)d_in[0];
    const unsigned char* bpe_mask = (const unsigned char*)d_in[1];
    const unsigned char* word_mask = (const unsigned char*)d_in[2];
    const int*  seg_ids     = (const int*)d_in[3];
    const void* tok_emb = d_in[4];

    detect_kernel<<<dim3(1), dim3(256), 0, stream>>>(
        byte_tokens, bpe_mask, word_mask, seg_ids,
        (const unsigned int*)tok_emb, flags);

    convert_weights<<<dim3((WB_TOTAL + 255) / 256), dim3(256), 0, stream>>>(
        d_in[5], d_in[6], d_in[7], d_in[8], d_in[9], d_in[10],
        d_in[11], d_in[12], d_in[13], d_in[14], d_in[15], d_in[16],
        d_in[17], d_in[18], flags, WB);

    // WB element offsets
    short* c0wT = WB;            short* c0b  = WB + 98304;
    short* h0gT = WB + 98816;    short* h0bg = WB + 623104;
    short* h0hT = WB + 624128;   short* h0bh = WB + 1148416;
    short* c1wT = WB + 1149440;  short* c1b  = WB + 1935872;
    short* h1gT = WB + 1936384;  short* h1bg = WB + 2460672;
    short* h1hT = WB + 2461696;  short* h1bh = WB + 2985984;
    short* pwT  = WB + 2987008;  short* pb   = WB + 3249152;
    const int LOFF = 262144, LBOFF = 512;   // per-highway-layer element offsets

    for (int b0 = 0; b0 < 8; b0 += C) {
        const int rows  = C * T_SEQ;
        const int words = C * 1024;
        char*  chunk  = ws + WBREG;
        short* xe     = (short*)chunk;                              // rows*64
        short* U      = (short*)(chunk + (size_t)C * 524288);       // rows*512
        short* V      = (short*)(chunk + (size_t)C * (524288 + 4194304));
        int*   wstart = (int*)(chunk + (size_t)C * 8912896);
        int*   wend   = wstart + words;
        short* segout = U;                                          // U dead by then

        embed_kernel<<<dim3(rows * 64 / 256), dim3(256), 0, stream>>>(
            byte_tokens, bpe_mask, word_mask, tok_emb, flags, xe, b0 * T_SEQ);

        dim3 gg(4, rows / 128);
        conv_mfma<64, false><<<gg, dim3(256), 0, stream>>>(xe, c0wT, c0b, U);

        highway_mfma<<<gg, dim3(256), 0, stream>>>(U, h0gT, h0bg, h0hT, h0bh, V);
        highway_mfma<<<gg, dim3(256), 0, stream>>>(V, h0gT + LOFF, h0bg + LBOFF,
                                                   h0hT + LOFF, h0bh + LBOFF, U);

        conv_mfma<512, true><<<gg, dim3(256), 0, stream>>>(U, c1wT, c1b, V);

        highway_mfma<<<gg, dim3(256), 0, stream>>>(V, h1gT, h1bg, h1hT, h1bh, U);
        highway_mfma<<<gg, dim3(256), 0, stream>>>(U, h1gT + LOFF, h1bg + LBOFF,
                                                   h1hT + LOFF, h1bh + LBOFF, V);

        bounds_kernel<<<dim3(rows / 256), dim3(256), 0, stream>>>(
            seg_ids, flags, wstart, wend, b0 * T_SEQ);

        segmax_kernel<<<dim3(words), dim3(512), 0, stream>>>(V, wstart, wend, segout);

        proj_mfma<<<dim3(4, words / 128), dim3(256), 0, stream>>>(
            segout, pwT, pb, flags, d_out, b0 * 1024);
    }
}

// Round 8
// 658.869 us; speedup vs baseline: 8.6133x; 1.0689x over previous
//
#include <hip/hip_runtime.h>
#include <hip/hip_bf16.h>

using bf16 = __hip_bfloat16;
typedef __attribute__((ext_vector_type(8))) short s8v;   // 8 bf16 in 4 VGPRs
typedef __attribute__((ext_vector_type(4))) float f4v;   // mfma accumulator

#define T_SEQ 4096
#define DWC 512

__device__ __forceinline__ float fin(float v) {
    return (v == v && fabsf(v) < 1e30f) ? v : 0.0f;
}
__device__ __forceinline__ float ldf(const void* p, size_t i, int f32) {
    return f32 ? ((const float*)p)[i] : __bfloat162float(((const bf16*)p)[i]);
}
__device__ __forceinline__ float b2f(short s) {
    unsigned u = ((unsigned)(unsigned short)s) << 16;
    return __builtin_bit_cast(float, u);
}
__device__ __forceinline__ short f2b(float v) {
    bf16 b = __float2bfloat16(v);
    return __builtin_bit_cast(short, b);
}

// XCD-aware swizzle: grid G (multiple of 32), NB=4 N-blocks.
// xcd = L&7; all 4 N-blocks of an M-tile land on the SAME XCD, and each XCD
// owns a contiguous band of M-tiles -> per-XCD L2 working set ~3.7MB < 4MiB.
__device__ __forceinline__ void swz(int L, int G, int& bx, int& by) {
    int k8 = L & 7, sl = L >> 3;
    int gp = G >> 5;              // M-tiles per XCD = G/(8*4)
    bx = sl & 3;
    by = k8 * gp + (sl >> 2);
}

// ---------------------------------------------------------------- diagnostics
__global__ __launch_bounds__(256) void diag_kernel(bf16* __restrict__ out, int n, float v)
{
    int i = blockIdx.x * 256 + threadIdx.x;
    if (i < n) out[i] = __float2bfloat16(i == 0 ? v : 0.0f);
}

// flags[0]=tok is64, flags[1]=bpe width{1,4,8}, flags[2]=wm width, flags[3]=seg is64,
// flags[4]=float width (1=fp32, 0=bf16)
__global__ __launch_bounds__(256) void detect_kernel(
    const int* __restrict__ tok, const unsigned char* __restrict__ bpe,
    const unsigned char* __restrict__ wm, const int* __restrict__ seg,
    const unsigned int* __restrict__ embw, int* __restrict__ flags)
{
    __shared__ int sh[5];
    int tid = threadIdx.x;
    if (tid < 5) sh[tid] = 0;
    __syncthreads();
    int bo = 0, bm = 0, wo = 0, wmid = 0;
    for (int i = tid; i < 16384; i += 256) {
        int odd = 2 * i + 1;
        if (bpe[odd]) bo = 1;
        if (wm[odd])  wo = 1;
        int mid = 8 * (i & 4095) + 4;
        if (bpe[mid]) bm = 1;
        if (wm[mid])  wmid = 1;
    }
    if (bo)   atomicOr(&sh[0], 1);
    if (bm)   atomicOr(&sh[1], 1);
    if (wo)   atomicOr(&sh[2], 1);
    if (wmid) atomicOr(&sh[3], 1);
    if (tid < 32 && embw[32 + tid] != 0u) atomicOr(&sh[4], 1);
    __syncthreads();
    if (tid == 0) {
        flags[0] = (tok[32767] != 0) ? 0 : 1;
        flags[1] = sh[0] ? 1 : (sh[1] ? 4 : 8);
        flags[2] = sh[2] ? 1 : (sh[3] ? 4 : 8);
        flags[3] = (seg[32767] != 0) ? 0 : 1;
        flags[4] = sh[4] ? 0 : 1;
    }
}

// ------------------------------------------------- weight convert + transpose
#define WB_TOTAL 3249664
__global__ __launch_bounds__(256) void convert_weights(
    const void* c0w, const void* c0b, const void* h0g, const void* h0bg,
    const void* h0h, const void* h0bh, const void* c1w, const void* c1b,
    const void* h1g, const void* h1bg, const void* h1h, const void* h1bh,
    const void* pw, const void* pb, const int* __restrict__ flags,
    short* __restrict__ WB)
{
    int f32 = flags[4];
    size_t i = (size_t)blockIdx.x * 256 + threadIdx.x;
    if (i >= WB_TOTAL) return;
    const void* src; size_t si;
    if (i < 98304)        { size_t n = i / 192, k = i % 192; src = c0w; si = k * 512 + n; }
    else if (i < 98816)   { src = c0b;  si = i - 98304; }
    else if (i < 623104)  { size_t o = i - 98816;  size_t l = o >> 18; o &= 262143;
                            size_t n = o >> 9, k = o & 511; src = h0g; si = (l << 18) + k * 512 + n; }
    else if (i < 624128)  { src = h0bg; si = i - 623104; }
    else if (i < 1148416) { size_t o = i - 624128; size_t l = o >> 18; o &= 262143;
                            size_t n = o >> 9, k = o & 511; src = h0h; si = (l << 18) + k * 512 + n; }
    else if (i < 1149440) { src = h0bh; si = i - 1148416; }
    else if (i < 1935872) { size_t o = i - 1149440; size_t n = o / 1536, k = o % 1536;
                            src = c1w; si = k * 512 + n; }
    else if (i < 1936384) { src = c1b;  si = i - 1935872; }
    else if (i < 2460672) { size_t o = i - 1936384; size_t l = o >> 18; o &= 262143;
                            size_t n = o >> 9, k = o & 511; src = h1g; si = (l << 18) + k * 512 + n; }
    else if (i < 2461696) { src = h1bg; si = i - 2460672; }
    else if (i < 2985984) { size_t o = i - 2461696; size_t l = o >> 18; o &= 262143;
                            size_t n = o >> 9, k = o & 511; src = h1h; si = (l << 18) + k * 512 + n; }
    else if (i < 2987008) { src = h1bh; si = i - 2985984; }
    else if (i < 3249152) { size_t o = i - 2987008; size_t n = o >> 9, k = o & 511;
                            src = pw; si = k * 512 + n; }
    else                  { src = pb;   si = i - 3249152; }
    WB[i] = f2b(ldf(src, si, f32));
}

// ---------------------------------------------------------------- embed
__global__ __launch_bounds__(256) void embed_kernel(
    const int* __restrict__ tok, const unsigned char* __restrict__ bpe,
    const unsigned char* __restrict__ wm, const void* __restrict__ emb,
    const int* __restrict__ flags, short* __restrict__ xe, int bt0)
{
    int i = blockIdx.x * 256 + threadIdx.x;
    int d = i & 63;
    int btl = i >> 6;
    int bt = bt0 + btl;
    int is64t = flags[0];
    int wb = flags[1], ww = flags[2];
    int f32 = flags[4];
    int t = is64t ? (int)((const long long*)tok)[bt] : tok[bt];
    t = min(max(t, 0), 263);
    float v = ldf(emb, (size_t)t * 64 + d, f32);
    if (bpe[(size_t)bt * wb]) v += ldf(emb, 4 * 64 + d, f32);
    if (wm[(size_t)bt * ww])  v += ldf(emb, 3 * 64 + d, f32);
    xe[i] = f2b(fin(v));
}

// ------------------------------------------------- MFMA conv-as-GEMM
template<int IC, bool RESID>
__global__ __launch_bounds__(256) void conv_mfma(
    const short* __restrict__ A, const short* __restrict__ WT,
    const short* __restrict__ bias, short* __restrict__ Out)
{
    constexpr int K = 3 * IC;
    __shared__ __align__(16) short As[128][40];
    __shared__ __align__(16) short Bs[128][40];
    int bx, by;
    swz(blockIdx.x, gridDim.x, bx, by);
    const int bm = by * 128;
    const int bn = bx * 128;
    const int tid = threadIdx.x;
    const int wave = tid >> 6, lane = tid & 63;
    const int wm = (wave >> 1) * 64, wn = (wave & 1) * 64;
    const int q = lane >> 4, ln16 = lane & 15;

    f4v acc[4][4] = {};

    for (int k0 = 0; k0 < K; k0 += 32) {
        const int tap = k0 / IC;
        const int c0 = k0 - tap * IC;
        #pragma unroll
        for (int it = 0; it < 2; it++) {
            int el = (tid + it * 256) * 8;
            int r = el >> 5, c = el & 31;
            int gr = bm + r;
            int t = gr & (T_SEQ - 1);
            int ts = t + tap - 1;
            uint4 va = make_uint4(0, 0, 0, 0);
            if (ts >= 0 && ts < T_SEQ)
                va = *(const uint4*)(A + (size_t)(gr + tap - 1) * IC + c0 + c);
            *(uint4*)(&As[r][c]) = va;
            *(uint4*)(&Bs[r][c]) = *(const uint4*)(WT + (size_t)(bn + r) * K + k0 + c);
        }
        __syncthreads();
        s8v af[4], bf[4];
        #pragma unroll
        for (int mi = 0; mi < 4; mi++) af[mi] = *(const s8v*)(&As[wm + mi * 16 + ln16][q * 8]);
        #pragma unroll
        for (int ni = 0; ni < 4; ni++) bf[ni] = *(const s8v*)(&Bs[wn + ni * 16 + ln16][q * 8]);
        #pragma unroll
        for (int mi = 0; mi < 4; mi++)
            #pragma unroll
            for (int ni = 0; ni < 4; ni++)
                acc[mi][ni] = __builtin_amdgcn_mfma_f32_16x16x32_bf16(
                    af[mi], bf[ni], acc[mi][ni], 0, 0, 0);
        __syncthreads();
    }

    #pragma unroll
    for (int mi = 0; mi < 4; mi++)
        #pragma unroll
        for (int ni = 0; ni < 4; ni++) {
            int col = bn + wn + ni * 16 + ln16;
            float bv = b2f(bias[col]);
            #pragma unroll
            for (int r = 0; r < 4; r++) {
                int row = bm + wm + mi * 16 + q * 4 + r;
                float v = acc[mi][ni][r] + bv;
                if constexpr (RESID) v += b2f(A[(size_t)row * IC + col]);
                Out[(size_t)row * DWC + col] = f2b(fin(fmaxf(v, 0.0f)));
            }
        }
}

// ------------------------------------------------- MFMA highway (dual GEMM)
__global__ __launch_bounds__(256) void highway_mfma(
    const short* __restrict__ Y, const short* __restrict__ WgT,
    const short* __restrict__ bg, const short* __restrict__ WhT,
    const short* __restrict__ bh, short* __restrict__ Out)
{
    __shared__ __align__(16) short As[128][40];
    __shared__ __align__(16) short Bg[128][40];
    __shared__ __align__(16) short Bh[128][40];
    int bx, by;
    swz(blockIdx.x, gridDim.x, bx, by);
    const int bm = by * 128;
    const int bn = bx * 128;
    const int tid = threadIdx.x;
    const int wave = tid >> 6, lane = tid & 63;
    const int wm = (wave >> 1) * 64, wn = (wave & 1) * 64;
    const int q = lane >> 4, ln16 = lane & 15;

    f4v accg[4][4] = {};
    f4v acch[4][4] = {};

    for (int k0 = 0; k0 < DWC; k0 += 32) {
        #pragma unroll
        for (int it = 0; it < 2; it++) {
            int el = (tid + it * 256) * 8;
            int r = el >> 5, c = el & 31;
            *(uint4*)(&As[r][c]) = *(const uint4*)(Y + (size_t)(bm + r) * DWC + k0 + c);
            *(uint4*)(&Bg[r][c]) = *(const uint4*)(WgT + (size_t)(bn + r) * DWC + k0 + c);
            *(uint4*)(&Bh[r][c]) = *(const uint4*)(WhT + (size_t)(bn + r) * DWC + k0 + c);
        }
        __syncthreads();
        s8v af[4], bgf[4], bhf[4];
        #pragma unroll
        for (int mi = 0; mi < 4; mi++) af[mi] = *(const s8v*)(&As[wm + mi * 16 + ln16][q * 8]);
        #pragma unroll
        for (int ni = 0; ni < 4; ni++) {
            bgf[ni] = *(const s8v*)(&Bg[wn + ni * 16 + ln16][q * 8]);
            bhf[ni] = *(const s8v*)(&Bh[wn + ni * 16 + ln16][q * 8]);
        }
        #pragma unroll
        for (int mi = 0; mi < 4; mi++)
            #pragma unroll
            for (int ni = 0; ni < 4; ni++) {
                accg[mi][ni] = __builtin_amdgcn_mfma_f32_16x16x32_bf16(
                    af[mi], bgf[ni], accg[mi][ni], 0, 0, 0);
                acch[mi][ni] = __builtin_amdgcn_mfma_f32_16x16x32_bf16(
                    af[mi], bhf[ni], acch[mi][ni], 0, 0, 0);
            }
        __syncthreads();
    }

    #pragma unroll
    for (int mi = 0; mi < 4; mi++)
        #pragma unroll
        for (int ni = 0; ni < 4; ni++) {
            int col = bn + wn + ni * 16 + ln16;
            float bgv = b2f(bg[col]);
            float bhv = b2f(bh[col]);
            #pragma unroll
            for (int r = 0; r < 4; r++) {
                int row = bm + wm + mi * 16 + q * 4 + r;
                float g = 1.0f / (1.0f + expf(-(accg[mi][ni][r] + bgv)));
                float h = fmaxf(acch[mi][ni][r] + bhv, 0.0f);
                float y = b2f(Y[(size_t)row * DWC + col]);
                Out[(size_t)row * DWC + col] = f2b(fin(g * h + (1.0f - g) * y));
            }
        }
}

// ------------------------------------------------- MFMA projection
__global__ __launch_bounds__(256) void proj_mfma(
    const short* __restrict__ A, const short* __restrict__ WT,
    const short* __restrict__ bias, const int* __restrict__ flags,
    void* __restrict__ Out, int oroff)
{
    __shared__ __align__(16) short As[128][40];
    __shared__ __align__(16) short Bs[128][40];
    int bx, by;
    swz(blockIdx.x, gridDim.x, bx, by);
    const int bm = by * 128;
    const int bn = bx * 128;
    const int tid = threadIdx.x;
    const int wave = tid >> 6, lane = tid & 63;
    const int wm = (wave >> 1) * 64, wn = (wave & 1) * 64;
    const int q = lane >> 4, ln16 = lane & 15;
    const int f32 = flags[4];

    f4v acc[4][4] = {};

    for (int k0 = 0; k0 < DWC; k0 += 32) {
        #pragma unroll
        for (int it = 0; it < 2; it++) {
            int el = (tid + it * 256) * 8;
            int r = el >> 5, c = el & 31;
            *(uint4*)(&As[r][c]) = *(const uint4*)(A + (size_t)(bm + r) * DWC + k0 + c);
            *(uint4*)(&Bs[r][c]) = *(const uint4*)(WT + (size_t)(bn + r) * DWC + k0 + c);
        }
        __syncthreads();
        s8v af[4], bf[4];
        #pragma unroll
        for (int mi = 0; mi < 4; mi++) af[mi] = *(const s8v*)(&As[wm + mi * 16 + ln16][q * 8]);
        #pragma unroll
        for (int ni = 0; ni < 4; ni++) bf[ni] = *(const s8v*)(&Bs[wn + ni * 16 + ln16][q * 8]);
        #pragma unroll
        for (int mi = 0; mi < 4; mi++)
            #pragma unroll
            for (int ni = 0; ni < 4; ni++)
                acc[mi][ni] = __builtin_amdgcn_mfma_f32_16x16x32_bf16(
                    af[mi], bf[ni], acc[mi][ni], 0, 0, 0);
        __syncthreads();
    }

    #pragma unroll
    for (int mi = 0; mi < 4; mi++)
        #pragma unroll
        for (int ni = 0; ni < 4; ni++) {
            int col = bn + wn + ni * 16 + ln16;
            float bv = b2f(bias[col]);
            #pragma unroll
            for (int r = 0; r < 4; r++) {
                int row = bm + wm + mi * 16 + q * 4 + r;
                float v = fin(acc[mi][ni][r] + bv);
                size_t oi = (size_t)(oroff + row) * DWC + col;
                if (f32) ((float*)Out)[oi] = v;
                else     ((bf16*)Out)[oi] = __float2bfloat16(v);
            }
        }
}

// ---------------------------------------------------------------- bounds / segmax
__global__ __launch_bounds__(256) void bounds_kernel(
    const int* __restrict__ seg, const int* __restrict__ flags,
    int* __restrict__ wstart, int* __restrict__ wend, int bt0)
{
    int il = blockIdx.x * 256 + threadIdx.x;
    int ig = bt0 + il;
    int is64 = flags[3];
    const long long* seg64 = (const long long*)seg;
    int t = il & (T_SEQ - 1);
    int bl = il >> 12;
    int s  = (is64 ? (int)seg64[ig] : seg[ig]) & 1023;
    int sp = (t == 0)         ? -1 : ((is64 ? (int)seg64[ig - 1] : seg[ig - 1]) & 1023);
    int sn = (t == T_SEQ - 1) ? -1 : ((is64 ? (int)seg64[ig + 1] : seg[ig + 1]) & 1023);
    int bw = (bl << 10) + s;
    if (sp != s) wstart[bw] = t;
    if (sn != s) wend[bw] = t;
}

__global__ __launch_bounds__(512) void segmax_kernel(
    const short* __restrict__ Y, const int* __restrict__ wstart,
    const int* __restrict__ wend, short* __restrict__ Out)
{
    int bw = blockIdx.x;
    int d = threadIdx.x;
    int bl = bw >> 10;
    int s = wstart[bw], e = wend[bw];
    s = min(max(s, 0), T_SEQ - 1);
    e = min(max(e, s), T_SEQ - 1);
    float m = b2f(Y[(size_t)((bl << 12) + s) * DWC + d]);
    for (int t = s + 1; t <= e; ++t)
        m = fmaxf(m, b2f(Y[(size_t)((bl << 12) + t) * DWC + d]));
    Out[(size_t)bw * DWC + d] = f2b(fin(m));
}

// ---------------------------------------------------------------- launch
extern "C" void kernel_launch(void* const* d_in, const int* in_sizes, int n_in,
                              void* d_out, int out_size, void* d_ws, size_t ws_size,
                              hipStream_t stream)
{
    static const int expect[19] = {32768, 32768, 32768, 32768, 16896,
                                   98304, 512, 524288, 1024, 524288, 1024,
                                   786432, 512, 524288, 1024, 524288, 1024,
                                   262144, 512};
    int bad = -1;
    if (n_in < 19) bad = 31;
    else for (int i = 0; i < 19; i++) if (in_sizes[i] != expect[i]) { bad = i; break; }
    if (bad >= 0) {
        diag_kernel<<<dim3((out_size + 255) / 256), dim3(256), 0, stream>>>(
            (bf16*)d_out, out_size, 1e35f * (float)(1 + bad));
        return;
    }

    char* ws = (char*)d_ws;
    const size_t WBREG = 8ull << 20;
    short* WB    = (short*)ws;
    int*   flags = (int*)(ws + 6500352);
    const size_t perC = 8921088 + 8192 + 64;
    int C = 8;
    while (C > 1 && WBREG + (size_t)C * perC > ws_size) C >>= 1;
    if (WBREG + (size_t)C * perC > ws_size) {
        float ws_mib = (float)((double)ws_size / 1048576.0);
        diag_kernel<<<dim3((out_size + 255) / 256), dim3(256), 0, stream>>>(
            (bf16*)d_out, out_size, 1e30f * (16.0f + ws_mib));
        return;
    }

    const int*  byte_tokens = (const int*)d_in[0];
    const unsigned char* bpe_mask = (const unsigned char*)d_in[1];
    const unsigned char* word_mask = (const unsigned char*)d_in[2];
    const int*  seg_ids     = (const int*)d_in[3];
    const void* tok_emb = d_in[4];

    detect_kernel<<<dim3(1), dim3(256), 0, stream>>>(
        byte_tokens, bpe_mask, word_mask, seg_ids,
        (const unsigned int*)tok_emb, flags);

    convert_weights<<<dim3((WB_TOTAL + 255) / 256), dim3(256), 0, stream>>>(
        d_in[5], d_in[6], d_in[7], d_in[8], d_in[9], d_in[10],
        d_in[11], d_in[12], d_in[13], d_in[14], d_in[15], d_in[16],
        d_in[17], d_in[18], flags, WB);

    short* c0wT = WB;            short* c0b  = WB + 98304;
    short* h0gT = WB + 98816;    short* h0bg = WB + 623104;
    short* h0hT = WB + 624128;   short* h0bh = WB + 1148416;
    short* c1wT = WB + 1149440;  short* c1b  = WB + 1935872;
    short* h1gT = WB + 1936384;  short* h1bg = WB + 2460672;
    short* h1hT = WB + 2461696;  short* h1bh = WB + 2985984;
    short* pwT  = WB + 2987008;  short* pb   = WB + 3249152;
    const int LOFF = 262144, LBOFF = 512;

    for (int b0 = 0; b0 < 8; b0 += C) {
        const int rows  = C * T_SEQ;
        const int words = C * 1024;
        char*  chunk  = ws + WBREG;
        short* xe     = (short*)chunk;
        short* U      = (short*)(chunk + (size_t)C * 524288);
        short* V      = (short*)(chunk + (size_t)C * (524288 + 4194304));
        int*   wstart = (int*)(chunk + (size_t)C * 8912896);
        int*   wend   = wstart + words;
        short* segout = U;

        embed_kernel<<<dim3(rows * 64 / 256), dim3(256), 0, stream>>>(
            byte_tokens, bpe_mask, word_mask, tok_emb, flags, xe, b0 * T_SEQ);

        dim3 gg(4 * (rows / 128));   // 1D swizzled grid
        conv_mfma<64, false><<<gg, dim3(256), 0, stream>>>(xe, c0wT, c0b, U);

        highway_mfma<<<gg, dim3(256), 0, stream>>>(U, h0gT, h0bg, h0hT, h0bh, V);
        highway_mfma<<<gg, dim3(256), 0, stream>>>(V, h0gT + LOFF, h0bg + LBOFF,
                                                   h0hT + LOFF, h0bh + LBOFF, U);

        conv_mfma<512, true><<<gg, dim3(256), 0, stream>>>(U, c1wT, c1b, V);

        highway_mfma<<<gg, dim3(256), 0, stream>>>(V, h1gT, h1bg, h1hT, h1bh, U);
        highway_mfma<<<gg, dim3(256), 0, stream>>>(U, h1gT + LOFF, h1bg + LBOFF,
                                                   h1hT + LOFF, h1bh + LBOFF, V);

        bounds_kernel<<<dim3(rows / 256), dim3(256), 0, stream>>>(
            seg_ids, flags, wstart, wend, b0 * T_SEQ);

        segmax_kernel<<<dim3(words), dim3(512), 0, stream>>>(V, wstart, wend, segout);

        proj_mfma<<<dim3(4 * (words / 128)), dim3(256), 0, stream>>>(
            segout, pwT, pb, flags, d_out, b0 * 1024);
    }
}

// Round 9
// 479.323 us; speedup vs baseline: 11.8397x; 1.3746x over previous
//
#include <hip/hip_runtime.h>
#include <hip/hip_bf16.h>

using bf16 = __hip_bfloat16;
typedef __attribute__((ext_vector_type(8))) short s8v;   // 8 bf16 in 4 VGPRs
typedef __attribute__((ext_vector_type(4))) float f4v;   // mfma accumulator

#define T_SEQ 4096
#define DWC 512

__device__ __forceinline__ float fin(float v) {
    return (v == v && fabsf(v) < 1e30f) ? v : 0.0f;
}
__device__ __forceinline__ float ldf(const void* p, size_t i, int f32) {
    return f32 ? ((const float*)p)[i] : __bfloat162float(((const bf16*)p)[i]);
}
__device__ __forceinline__ float b2f(short s) {
    unsigned u = ((unsigned)(unsigned short)s) << 16;
    return __builtin_bit_cast(float, u);
}
__device__ __forceinline__ short f2b(float v) {
    bf16 b = __float2bfloat16(v);
    return __builtin_bit_cast(short, b);
}

// XCD-aware swizzle (verified R8: conv1 FETCH 210->29MB): all 4 N-blocks of an
// M-tile on one XCD; contiguous M-band per XCD. G multiple of 32.
__device__ __forceinline__ void swz(int L, int G, int& bx, int& by) {
    int k8 = L & 7, sl = L >> 3;
    int gp = G >> 5;
    bx = sl & 3;
    by = k8 * gp + (sl >> 2);
}

// ---------------------------------------------------------------- diagnostics
__global__ __launch_bounds__(256) void diag_kernel(bf16* __restrict__ out, int n, float v)
{
    int i = blockIdx.x * 256 + threadIdx.x;
    if (i < n) out[i] = __float2bfloat16(i == 0 ? v : 0.0f);
}

// flags[0]=tok is64, flags[1]=bpe width{1,4,8}, flags[2]=wm width, flags[3]=seg is64,
// flags[4]=float width (1=fp32, 0=bf16)
__global__ __launch_bounds__(256) void detect_kernel(
    const int* __restrict__ tok, const unsigned char* __restrict__ bpe,
    const unsigned char* __restrict__ wm, const int* __restrict__ seg,
    const unsigned int* __restrict__ embw, int* __restrict__ flags)
{
    __shared__ int sh[5];
    int tid = threadIdx.x;
    if (tid < 5) sh[tid] = 0;
    __syncthreads();
    int bo = 0, bm = 0, wo = 0, wmid = 0;
    for (int i = tid; i < 16384; i += 256) {
        int odd = 2 * i + 1;
        if (bpe[odd]) bo = 1;
        if (wm[odd])  wo = 1;
        int mid = 8 * (i & 4095) + 4;
        if (bpe[mid]) bm = 1;
        if (wm[mid])  wmid = 1;
    }
    if (bo)   atomicOr(&sh[0], 1);
    if (bm)   atomicOr(&sh[1], 1);
    if (wo)   atomicOr(&sh[2], 1);
    if (wmid) atomicOr(&sh[3], 1);
    if (tid < 32 && embw[32 + tid] != 0u) atomicOr(&sh[4], 1);
    __syncthreads();
    if (tid == 0) {
        flags[0] = (tok[32767] != 0) ? 0 : 1;
        flags[1] = sh[0] ? 1 : (sh[1] ? 4 : 8);
        flags[2] = sh[2] ? 1 : (sh[3] ? 4 : 8);
        flags[3] = (seg[32767] != 0) ? 0 : 1;
        flags[4] = sh[4] ? 0 : 1;
    }
}

// ------------------------------------------------- weight convert + transpose
#define WB_TOTAL 3249664
__global__ __launch_bounds__(256) void convert_weights(
    const void* c0w, const void* c0b, const void* h0g, const void* h0bg,
    const void* h0h, const void* h0bh, const void* c1w, const void* c1b,
    const void* h1g, const void* h1bg, const void* h1h, const void* h1bh,
    const void* pw, const void* pb, const int* __restrict__ flags,
    short* __restrict__ WB)
{
    int f32 = flags[4];
    size_t i = (size_t)blockIdx.x * 256 + threadIdx.x;
    if (i >= WB_TOTAL) return;
    const void* src; size_t si;
    if (i < 98304)        { size_t n = i / 192, k = i % 192; src = c0w; si = k * 512 + n; }
    else if (i < 98816)   { src = c0b;  si = i - 98304; }
    else if (i < 623104)  { size_t o = i - 98816;  size_t l = o >> 18; o &= 262143;
                            size_t n = o >> 9, k = o & 511; src = h0g; si = (l << 18) + k * 512 + n; }
    else if (i < 624128)  { src = h0bg; si = i - 623104; }
    else if (i < 1148416) { size_t o = i - 624128; size_t l = o >> 18; o &= 262143;
                            size_t n = o >> 9, k = o & 511; src = h0h; si = (l << 18) + k * 512 + n; }
    else if (i < 1149440) { src = h0bh; si = i - 1148416; }
    else if (i < 1935872) { size_t o = i - 1149440; size_t n = o / 1536, k = o % 1536;
                            src = c1w; si = k * 512 + n; }
    else if (i < 1936384) { src = c1b;  si = i - 1935872; }
    else if (i < 2460672) { size_t o = i - 1936384; size_t l = o >> 18; o &= 262143;
                            size_t n = o >> 9, k = o & 511; src = h1g; si = (l << 18) + k * 512 + n; }
    else if (i < 2461696) { src = h1bg; si = i - 2460672; }
    else if (i < 2985984) { size_t o = i - 2461696; size_t l = o >> 18; o &= 262143;
                            size_t n = o >> 9, k = o & 511; src = h1h; si = (l << 18) + k * 512 + n; }
    else if (i < 2987008) { src = h1bh; si = i - 2985984; }
    else if (i < 3249152) { size_t o = i - 2987008; size_t n = o >> 9, k = o & 511;
                            src = pw; si = k * 512 + n; }
    else                  { src = pb;   si = i - 3249152; }
    WB[i] = f2b(ldf(src, si, f32));
}

// ---------------------------------------------------------------- embed
__global__ __launch_bounds__(256) void embed_kernel(
    const int* __restrict__ tok, const unsigned char* __restrict__ bpe,
    const unsigned char* __restrict__ wm, const void* __restrict__ emb,
    const int* __restrict__ flags, short* __restrict__ xe, int bt0)
{
    int i = blockIdx.x * 256 + threadIdx.x;
    int d = i & 63;
    int btl = i >> 6;
    int bt = bt0 + btl;
    int is64t = flags[0];
    int wb = flags[1], ww = flags[2];
    int f32 = flags[4];
    int t = is64t ? (int)((const long long*)tok)[bt] : tok[bt];
    t = min(max(t, 0), 263);
    float v = ldf(emb, (size_t)t * 64 + d, f32);
    if (bpe[(size_t)bt * wb]) v += ldf(emb, 4 * 64 + d, f32);
    if (wm[(size_t)bt * ww])  v += ldf(emb, 3 * 64 + d, f32);
    xe[i] = f2b(fin(v));
}

// ------------------------------------------------- MFMA conv-as-GEMM
// 512 threads, 128x128 tile, BK=32. 8 waves: each 32(M)x64(N) = 2x4 mfma.
// LDS unpadded [128][32]: staging writes flat tid*16B (conflict-free),
// frag reads lane-distinct 16B spans (conflict-free).
template<int IC, bool RESID>
__global__ __launch_bounds__(512) void conv_mfma(
    const short* __restrict__ A, const short* __restrict__ WT,
    const short* __restrict__ bias, short* __restrict__ Out)
{
    constexpr int K = 3 * IC;
    __shared__ __align__(16) short As[128 * 32];
    __shared__ __align__(16) short Bs[128 * 32];
    int bx, by;
    swz(blockIdx.x, gridDim.x, bx, by);
    const int bm = by * 128;
    const int bn = bx * 128;
    const int tid = threadIdx.x;
    const int wave = tid >> 6, lane = tid & 63;
    const int wmr = (wave >> 1) * 32, wnc = (wave & 1) * 64;
    const int q = lane >> 4, ln16 = lane & 15;
    const int sr = tid >> 2, sc = (tid & 3) * 8;   // staging row/col

    f4v acc[2][4] = {};

    for (int k0 = 0; k0 < K; k0 += 32) {
        const int tap = k0 / IC;
        const int c0 = k0 - tap * IC;
        {
            int gr = bm + sr;
            int tt = gr & (T_SEQ - 1);
            int ts = tt + tap - 1;
            uint4 va = make_uint4(0, 0, 0, 0);
            if (ts >= 0 && ts < T_SEQ)
                va = *(const uint4*)(A + (size_t)(gr + tap - 1) * IC + c0 + sc);
            *(uint4*)(&As[sr * 32 + sc]) = va;
            *(uint4*)(&Bs[sr * 32 + sc]) = *(const uint4*)(WT + (size_t)(bn + sr) * K + k0 + sc);
        }
        __syncthreads();
        s8v af[2], bf[4];
        #pragma unroll
        for (int mi = 0; mi < 2; mi++) af[mi] = *(const s8v*)(&As[(wmr + mi * 16 + ln16) * 32 + q * 8]);
        #pragma unroll
        for (int ni = 0; ni < 4; ni++) bf[ni] = *(const s8v*)(&Bs[(wnc + ni * 16 + ln16) * 32 + q * 8]);
        #pragma unroll
        for (int mi = 0; mi < 2; mi++)
            #pragma unroll
            for (int ni = 0; ni < 4; ni++)
                acc[mi][ni] = __builtin_amdgcn_mfma_f32_16x16x32_bf16(
                    af[mi], bf[ni], acc[mi][ni], 0, 0, 0);
        __syncthreads();
    }

    #pragma unroll
    for (int mi = 0; mi < 2; mi++)
        #pragma unroll
        for (int ni = 0; ni < 4; ni++) {
            int col = bn + wnc + ni * 16 + ln16;
            float bv = b2f(bias[col]);
            #pragma unroll
            for (int r = 0; r < 4; r++) {
                int row = bm + wmr + mi * 16 + q * 4 + r;
                float v = acc[mi][ni][r] + bv;
                if constexpr (RESID) v += b2f(A[(size_t)row * IC + col]);
                Out[(size_t)row * DWC + col] = f2b(fin(fmaxf(v, 0.0f)));
            }
        }
}

// ------------------------------------------------- MFMA highway (dual GEMM)
__global__ __launch_bounds__(512) void highway_mfma(
    const short* __restrict__ Y, const short* __restrict__ WgT,
    const short* __restrict__ bg, const short* __restrict__ WhT,
    const short* __restrict__ bh, short* __restrict__ Out)
{
    __shared__ __align__(16) short As[128 * 32];
    __shared__ __align__(16) short Bg[128 * 32];
    __shared__ __align__(16) short Bh[128 * 32];
    int bx, by;
    swz(blockIdx.x, gridDim.x, bx, by);
    const int bm = by * 128;
    const int bn = bx * 128;
    const int tid = threadIdx.x;
    const int wave = tid >> 6, lane = tid & 63;
    const int wmr = (wave >> 1) * 32, wnc = (wave & 1) * 64;
    const int q = lane >> 4, ln16 = lane & 15;
    const int sr = tid >> 2, sc = (tid & 3) * 8;

    f4v accg[2][4] = {};
    f4v acch[2][4] = {};

    for (int k0 = 0; k0 < DWC; k0 += 32) {
        *(uint4*)(&As[sr * 32 + sc]) = *(const uint4*)(Y + (size_t)(bm + sr) * DWC + k0 + sc);
        *(uint4*)(&Bg[sr * 32 + sc]) = *(const uint4*)(WgT + (size_t)(bn + sr) * DWC + k0 + sc);
        *(uint4*)(&Bh[sr * 32 + sc]) = *(const uint4*)(WhT + (size_t)(bn + sr) * DWC + k0 + sc);
        __syncthreads();
        s8v af[2], bgf[4], bhf[4];
        #pragma unroll
        for (int mi = 0; mi < 2; mi++) af[mi] = *(const s8v*)(&As[(wmr + mi * 16 + ln16) * 32 + q * 8]);
        #pragma unroll
        for (int ni = 0; ni < 4; ni++) {
            bgf[ni] = *(const s8v*)(&Bg[(wnc + ni * 16 + ln16) * 32 + q * 8]);
            bhf[ni] = *(const s8v*)(&Bh[(wnc + ni * 16 + ln16) * 32 + q * 8]);
        }
        #pragma unroll
        for (int mi = 0; mi < 2; mi++)
            #pragma unroll
            for (int ni = 0; ni < 4; ni++) {
                accg[mi][ni] = __builtin_amdgcn_mfma_f32_16x16x32_bf16(
                    af[mi], bgf[ni], accg[mi][ni], 0, 0, 0);
                acch[mi][ni] = __builtin_amdgcn_mfma_f32_16x16x32_bf16(
                    af[mi], bhf[ni], acch[mi][ni], 0, 0, 0);
            }
        __syncthreads();
    }

    #pragma unroll
    for (int mi = 0; mi < 2; mi++)
        #pragma unroll
        for (int ni = 0; ni < 4; ni++) {
            int col = bn + wnc + ni * 16 + ln16;
            float bgv = b2f(bg[col]);
            float bhv = b2f(bh[col]);
            #pragma unroll
            for (int r = 0; r < 4; r++) {
                int row = bm + wmr + mi * 16 + q * 4 + r;
                float g = 1.0f / (1.0f + expf(-(accg[mi][ni][r] + bgv)));
                float h = fmaxf(acch[mi][ni][r] + bhv, 0.0f);
                float y = b2f(Y[(size_t)row * DWC + col]);
                Out[(size_t)row * DWC + col] = f2b(fin(g * h + (1.0f - g) * y));
            }
        }
}

// ------------------------------------------------- MFMA projection
__global__ __launch_bounds__(512) void proj_mfma(
    const short* __restrict__ A, const short* __restrict__ WT,
    const short* __restrict__ bias, const int* __restrict__ flags,
    void* __restrict__ Out, int oroff)
{
    __shared__ __align__(16) short As[128 * 32];
    __shared__ __align__(16) short Bs[128 * 32];
    int bx, by;
    swz(blockIdx.x, gridDim.x, bx, by);
    const int bm = by * 128;
    const int bn = bx * 128;
    const int tid = threadIdx.x;
    const int wave = tid >> 6, lane = tid & 63;
    const int wmr = (wave >> 1) * 32, wnc = (wave & 1) * 64;
    const int q = lane >> 4, ln16 = lane & 15;
    const int sr = tid >> 2, sc = (tid & 3) * 8;
    const int f32 = flags[4];

    f4v acc[2][4] = {};

    for (int k0 = 0; k0 < DWC; k0 += 32) {
        *(uint4*)(&As[sr * 32 + sc]) = *(const uint4*)(A + (size_t)(bm + sr) * DWC + k0 + sc);
        *(uint4*)(&Bs[sr * 32 + sc]) = *(const uint4*)(WT + (size_t)(bn + sr) * DWC + k0 + sc);
        __syncthreads();
        s8v af[2], bf[4];
        #pragma unroll
        for (int mi = 0; mi < 2; mi++) af[mi] = *(const s8v*)(&As[(wmr + mi * 16 + ln16) * 32 + q * 8]);
        #pragma unroll
        for (int ni = 0; ni < 4; ni++) bf[ni] = *(const s8v*)(&Bs[(wnc + ni * 16 + ln16) * 32 + q * 8]);
        #pragma unroll
        for (int mi = 0; mi < 2; mi++)
            #pragma unroll
            for (int ni = 0; ni < 4; ni++)
                acc[mi][ni] = __builtin_amdgcn_mfma_f32_16x16x32_bf16(
                    af[mi], bf[ni], acc[mi][ni], 0, 0, 0);
        __syncthreads();
    }

    #pragma unroll
    for (int mi = 0; mi < 2; mi++)
        #pragma unroll
        for (int ni = 0; ni < 4; ni++) {
            int col = bn + wnc + ni * 16 + ln16;
            float bv = b2f(bias[col]);
            #pragma unroll
            for (int r = 0; r < 4; r++) {
                int row = bm + wmr + mi * 16 + q * 4 + r;
                float v = fin(acc[mi][ni][r] + bv);
                size_t oi = (size_t)(oroff + row) * DWC + col;
                if (f32) ((float*)Out)[oi] = v;
                else     ((bf16*)Out)[oi] = __float2bfloat16(v);
            }
        }
}

// ---------------------------------------------------------------- bounds / segmax
__global__ __launch_bounds__(256) void bounds_kernel(
    const int* __restrict__ seg, const int* __restrict__ flags,
    int* __restrict__ wstart, int* __restrict__ wend, int bt0)
{
    int il = blockIdx.x * 256 + threadIdx.x;
    int ig = bt0 + il;
    int is64 = flags[3];
    const long long* seg64 = (const long long*)seg;
    int t = il & (T_SEQ - 1);
    int bl = il >> 12;
    int s  = (is64 ? (int)seg64[ig] : seg[ig]) & 1023;
    int sp = (t == 0)         ? -1 : ((is64 ? (int)seg64[ig - 1] : seg[ig - 1]) & 1023);
    int sn = (t == T_SEQ - 1) ? -1 : ((is64 ? (int)seg64[ig + 1] : seg[ig + 1]) & 1023);
    int bw = (bl << 10) + s;
    if (sp != s) wstart[bw] = t;
    if (sn != s) wend[bw] = t;
}

__global__ __launch_bounds__(512) void segmax_kernel(
    const short* __restrict__ Y, const int* __restrict__ wstart,
    const int* __restrict__ wend, short* __restrict__ Out)
{
    int bw = blockIdx.x;
    int d = threadIdx.x;
    int bl = bw >> 10;
    int s = wstart[bw], e = wend[bw];
    s = min(max(s, 0), T_SEQ - 1);
    e = min(max(e, s), T_SEQ - 1);
    float m = b2f(Y[(size_t)((bl << 12) + s) * DWC + d]);
    for (int t = s + 1; t <= e; ++t)
        m = fmaxf(m, b2f(Y[(size_t)((bl << 12) + t) * DWC + d]));
    Out[(size_t)bw * DWC + d] = f2b(fin(m));
}

// ---------------------------------------------------------------- launch
extern "C" void kernel_launch(void* const* d_in, const int* in_sizes, int n_in,
                              void* d_out, int out_size, void* d_ws, size_t ws_size,
                              hipStream_t stream)
{
    static const int expect[19] = {32768, 32768, 32768, 32768, 16896,
                                   98304, 512, 524288, 1024, 524288, 1024,
                                   786432, 512, 524288, 1024, 524288, 1024,
                                   262144, 512};
    int bad = -1;
    if (n_in < 19) bad = 31;
    else for (int i = 0; i < 19; i++) if (in_sizes[i] != expect[i]) { bad = i; break; }
    if (bad >= 0) {
        diag_kernel<<<dim3((out_size + 255) / 256), dim3(256), 0, stream>>>(
            (bf16*)d_out, out_size, 1e35f * (float)(1 + bad));
        return;
    }

    char* ws = (char*)d_ws;
    const size_t WBREG = 8ull << 20;
    short* WB    = (short*)ws;
    int*   flags = (int*)(ws + 6500352);
    const size_t perC = 8921088 + 8192 + 64;
    int C = 8;
    while (C > 1 && WBREG + (size_t)C * perC > ws_size) C >>= 1;
    if (WBREG + (size_t)C * perC > ws_size) {
        float ws_mib = (float)((double)ws_size / 1048576.0);
        diag_kernel<<<dim3((out_size + 255) / 256), dim3(256), 0, stream>>>(
            (bf16*)d_out, out_size, 1e30f * (16.0f + ws_mib));
        return;
    }

    const int*  byte_tokens = (const int*)d_in[0];
    const unsigned char* bpe_mask = (const unsigned char*)d_in[1];
    const unsigned char* word_mask = (const unsigned char*)d_in[2];
    const int*  seg_ids     = (const int*)d_in[3];
    const void* tok_emb = d_in[4];

    detect_kernel<<<dim3(1), dim3(256), 0, stream>>>(
        byte_tokens, bpe_mask, word_mask, seg_ids,
        (const unsigned int*)tok_emb, flags);

    convert_weights<<<dim3((WB_TOTAL + 255) / 256), dim3(256), 0, stream>>>(
        d_in[5], d_in[6], d_in[7], d_in[8], d_in[9], d_in[10],
        d_in[11], d_in[12], d_in[13], d_in[14], d_in[15], d_in[16],
        d_in[17], d_in[18], flags, WB);

    short* c0wT = WB;            short* c0b  = WB + 98304;
    short* h0gT = WB + 98816;    short* h0bg = WB + 623104;
    short* h0hT = WB + 624128;   short* h0bh = WB + 1148416;
    short* c1wT = WB + 1149440;  short* c1b  = WB + 1935872;
    short* h1gT = WB + 1936384;  short* h1bg = WB + 2460672;
    short* h1hT = WB + 2461696;  short* h1bh = WB + 2985984;
    short* pwT  = WB + 2987008;  short* pb   = WB + 3249152;
    const int LOFF = 262144, LBOFF = 512;

    for (int b0 = 0; b0 < 8; b0 += C) {
        const int rows  = C * T_SEQ;
        const int words = C * 1024;
        char*  chunk  = ws + WBREG;
        short* xe     = (short*)chunk;
        short* U      = (short*)(chunk + (size_t)C * 524288);
        short* V      = (short*)(chunk + (size_t)C * (524288 + 4194304));
        int*   wstart = (int*)(chunk + (size_t)C * 8912896);
        int*   wend   = wstart + words;
        short* segout = U;

        embed_kernel<<<dim3(rows * 64 / 256), dim3(256), 0, stream>>>(
            byte_tokens, bpe_mask, word_mask, tok_emb, flags, xe, b0 * T_SEQ);

        dim3 gg(4 * (rows / 128));   // 1D swizzled grid
        conv_mfma<64, false><<<gg, dim3(512), 0, stream>>>(xe, c0wT, c0b, U);

        highway_mfma<<<gg, dim3(512), 0, stream>>>(U, h0gT, h0bg, h0hT, h0bh, V);
        highway_mfma<<<gg, dim3(512), 0, stream>>>(V, h0gT + LOFF, h0bg + LBOFF,
                                                   h0hT + LOFF, h0bh + LBOFF, U);

        conv_mfma<512, true><<<gg, dim3(512), 0, stream>>>(U, c1wT, c1b, V);

        highway_mfma<<<gg, dim3(512), 0, stream>>>(V, h1gT, h1bg, h1hT, h1bh, U);
        highway_mfma<<<gg, dim3(512), 0, stream>>>(U, h1gT + LOFF, h1bg + LBOFF,
                                                   h1hT + LOFF, h1bh + LBOFF, V);

        bounds_kernel<<<dim3(rows / 256), dim3(256), 0, stream>>>(
            seg_ids, flags, wstart, wend, b0 * T_SEQ);

        segmax_kernel<<<dim3(words), dim3(512), 0, stream>>>(V, wstart, wend, segout);

        proj_mfma<<<dim3(4 * (words / 128)), dim3(512), 0, stream>>>(
            segout, pwT, pb, flags, d_out, b0 * 1024);
    }
}

// Round 10
// 476.177 us; speedup vs baseline: 11.9179x; 1.0066x over previous
//
#include <hip/hip_runtime.h>
#include <hip/hip_bf16.h>

using bf16 = __hip_bfloat16;
typedef __attribute__((ext_vector_type(8))) short s8v;   // 8 bf16 in 4 VGPRs
typedef __attribute__((ext_vector_type(4))) float f4v;   // mfma accumulator

#define T_SEQ 4096
#define DWC 512

__device__ __forceinline__ float fin(float v) {
    return (v == v && fabsf(v) < 1e30f) ? v : 0.0f;
}
__device__ __forceinline__ float ldf(const void* p, size_t i, int f32) {
    return f32 ? ((const float*)p)[i] : __bfloat162float(((const bf16*)p)[i]);
}
__device__ __forceinline__ float b2f(short s) {
    unsigned u = ((unsigned)(unsigned short)s) << 16;
    return __builtin_bit_cast(float, u);
}
__device__ __forceinline__ short f2b(float v) {
    bf16 b = __float2bfloat16(v);
    return __builtin_bit_cast(short, b);
}

// XCD-aware swizzle (verified R8: conv1 FETCH 210->29MB).
__device__ __forceinline__ void swz(int L, int G, int& bx, int& by) {
    int k8 = L & 7, sl = L >> 3;
    int gp = G >> 5;
    bx = sl & 3;
    by = k8 * gp + (sl >> 2);
}

// LDS bank-XOR swizzle: 8-short chunk `ch` of row `row` (rows of 32 shorts).
// Makes both staging writes and frag reads <=2-way per 16-lane group (free, m136).
__device__ __forceinline__ int swidx(int row, int ch) {
    return row * 32 + ((ch ^ ((row >> 1) & 3)) << 3);
}

// ---------------------------------------------------------------- diagnostics
__global__ __launch_bounds__(256) void diag_kernel(bf16* __restrict__ out, int n, float v)
{
    int i = blockIdx.x * 256 + threadIdx.x;
    if (i < n) out[i] = __float2bfloat16(i == 0 ? v : 0.0f);
}

// flags[0]=tok is64, flags[1]=bpe width{1,4,8}, flags[2]=wm width, flags[3]=seg is64,
// flags[4]=float width (1=fp32, 0=bf16)
__global__ __launch_bounds__(256) void detect_kernel(
    const int* __restrict__ tok, const unsigned char* __restrict__ bpe,
    const unsigned char* __restrict__ wm, const int* __restrict__ seg,
    const unsigned int* __restrict__ embw, int* __restrict__ flags)
{
    __shared__ int sh[5];
    int tid = threadIdx.x;
    if (tid < 5) sh[tid] = 0;
    __syncthreads();
    int bo = 0, bm = 0, wo = 0, wmid = 0;
    for (int i = tid; i < 16384; i += 256) {
        int odd = 2 * i + 1;
        if (bpe[odd]) bo = 1;
        if (wm[odd])  wo = 1;
        int mid = 8 * (i & 4095) + 4;
        if (bpe[mid]) bm = 1;
        if (wm[mid])  wmid = 1;
    }
    if (bo)   atomicOr(&sh[0], 1);
    if (bm)   atomicOr(&sh[1], 1);
    if (wo)   atomicOr(&sh[2], 1);
    if (wmid) atomicOr(&sh[3], 1);
    if (tid < 32 && embw[32 + tid] != 0u) atomicOr(&sh[4], 1);
    __syncthreads();
    if (tid == 0) {
        flags[0] = (tok[32767] != 0) ? 0 : 1;
        flags[1] = sh[0] ? 1 : (sh[1] ? 4 : 8);
        flags[2] = sh[2] ? 1 : (sh[3] ? 4 : 8);
        flags[3] = (seg[32767] != 0) ? 0 : 1;
        flags[4] = sh[4] ? 0 : 1;
    }
}

// ------------------------------------------------- weight convert + transpose
#define WB_TOTAL 3249664
__global__ __launch_bounds__(256) void convert_weights(
    const void* c0w, const void* c0b, const void* h0g, const void* h0bg,
    const void* h0h, const void* h0bh, const void* c1w, const void* c1b,
    const void* h1g, const void* h1bg, const void* h1h, const void* h1bh,
    const void* pw, const void* pb, const int* __restrict__ flags,
    short* __restrict__ WB)
{
    int f32 = flags[4];
    size_t i = (size_t)blockIdx.x * 256 + threadIdx.x;
    if (i >= WB_TOTAL) return;
    const void* src; size_t si;
    if (i < 98304)        { size_t n = i / 192, k = i % 192; src = c0w; si = k * 512 + n; }
    else if (i < 98816)   { src = c0b;  si = i - 98304; }
    else if (i < 623104)  { size_t o = i - 98816;  size_t l = o >> 18; o &= 262143;
                            size_t n = o >> 9, k = o & 511; src = h0g; si = (l << 18) + k * 512 + n; }
    else if (i < 624128)  { src = h0bg; si = i - 623104; }
    else if (i < 1148416) { size_t o = i - 624128; size_t l = o >> 18; o &= 262143;
                            size_t n = o >> 9, k = o & 511; src = h0h; si = (l << 18) + k * 512 + n; }
    else if (i < 1149440) { src = h0bh; si = i - 1148416; }
    else if (i < 1935872) { size_t o = i - 1149440; size_t n = o / 1536, k = o % 1536;
                            src = c1w; si = k * 512 + n; }
    else if (i < 1936384) { src = c1b;  si = i - 1935872; }
    else if (i < 2460672) { size_t o = i - 1936384; size_t l = o >> 18; o &= 262143;
                            size_t n = o >> 9, k = o & 511; src = h1g; si = (l << 18) + k * 512 + n; }
    else if (i < 2461696) { src = h1bg; si = i - 2460672; }
    else if (i < 2985984) { size_t o = i - 2461696; size_t l = o >> 18; o &= 262143;
                            size_t n = o >> 9, k = o & 511; src = h1h; si = (l << 18) + k * 512 + n; }
    else if (i < 2987008) { src = h1bh; si = i - 2985984; }
    else if (i < 3249152) { size_t o = i - 2987008; size_t n = o >> 9, k = o & 511;
                            src = pw; si = k * 512 + n; }
    else                  { src = pb;   si = i - 3249152; }
    WB[i] = f2b(ldf(src, si, f32));
}

// ---------------------------------------------------------------- embed
__global__ __launch_bounds__(256) void embed_kernel(
    const int* __restrict__ tok, const unsigned char* __restrict__ bpe,
    const unsigned char* __restrict__ wm, const void* __restrict__ emb,
    const int* __restrict__ flags, short* __restrict__ xe, int bt0)
{
    int i = blockIdx.x * 256 + threadIdx.x;
    int d = i & 63;
    int btl = i >> 6;
    int bt = bt0 + btl;
    int is64t = flags[0];
    int wb = flags[1], ww = flags[2];
    int f32 = flags[4];
    int t = is64t ? (int)((const long long*)tok)[bt] : tok[bt];
    t = min(max(t, 0), 263);
    float v = ldf(emb, (size_t)t * 64 + d, f32);
    if (bpe[(size_t)bt * wb]) v += ldf(emb, 4 * 64 + d, f32);
    if (wm[(size_t)bt * ww])  v += ldf(emb, 3 * 64 + d, f32);
    xe[i] = f2b(fin(v));
}

// ------------------------------------------------- MFMA conv-as-GEMM
// 512 threads, 128x128 tile, BK=32, 8 waves of 32(M)x64(N).
// XOR-swizzled LDS + software prefetch of next K-tile.
template<int IC, bool RESID>
__global__ __launch_bounds__(512) void conv_mfma(
    const short* __restrict__ A, const short* __restrict__ WT,
    const short* __restrict__ bias, short* __restrict__ Out)
{
    constexpr int K = 3 * IC;
    __shared__ __align__(16) short As[128 * 32];
    __shared__ __align__(16) short Bs[128 * 32];
    int bx, by;
    swz(blockIdx.x, gridDim.x, bx, by);
    const int bm = by * 128;
    const int bn = bx * 128;
    const int tid = threadIdx.x;
    const int wave = tid >> 6, lane = tid & 63;
    const int wmr = (wave >> 1) * 32, wnc = (wave & 1) * 64;
    const int q = lane >> 4, ln16 = lane & 15;
    const int sr = tid >> 2, sch = tid & 3, sc = sch * 8;
    const int sw = swidx(sr, sch);

    f4v acc[2][4] = {};
    uint4 ra, rb;

    // prefetch iter 0
    {
        int gr = bm + sr;
        int tt = gr & (T_SEQ - 1);
        int ts = tt - 1;                       // tap 0
        ra = make_uint4(0, 0, 0, 0);
        if (ts >= 0 && ts < T_SEQ)
            ra = *(const uint4*)(A + (size_t)(gr - 1) * IC + sc);
        rb = *(const uint4*)(WT + (size_t)(bn + sr) * K + sc);
    }

    for (int k0 = 0; k0 < K; k0 += 32) {
        *(uint4*)(&As[sw]) = ra;
        *(uint4*)(&Bs[sw]) = rb;
        __syncthreads();
        if (k0 + 32 < K) {                     // prefetch next K-tile
            int kn = k0 + 32;
            int tap = kn / IC;
            int c0 = kn - tap * IC;
            int gr = bm + sr;
            int tt = gr & (T_SEQ - 1);
            int ts = tt + tap - 1;
            ra = make_uint4(0, 0, 0, 0);
            if (ts >= 0 && ts < T_SEQ)
                ra = *(const uint4*)(A + (size_t)(gr + tap - 1) * IC + c0 + sc);
            rb = *(const uint4*)(WT + (size_t)(bn + sr) * K + kn + sc);
        }
        s8v af[2], bf[4];
        #pragma unroll
        for (int mi = 0; mi < 2; mi++) af[mi] = *(const s8v*)(&As[swidx(wmr + mi * 16 + ln16, q)]);
        #pragma unroll
        for (int ni = 0; ni < 4; ni++) bf[ni] = *(const s8v*)(&Bs[swidx(wnc + ni * 16 + ln16, q)]);
        #pragma unroll
        for (int mi = 0; mi < 2; mi++)
            #pragma unroll
            for (int ni = 0; ni < 4; ni++)
                acc[mi][ni] = __builtin_amdgcn_mfma_f32_16x16x32_bf16(
                    af[mi], bf[ni], acc[mi][ni], 0, 0, 0);
        __syncthreads();
    }

    #pragma unroll
    for (int mi = 0; mi < 2; mi++)
        #pragma unroll
        for (int ni = 0; ni < 4; ni++) {
            int col = bn + wnc + ni * 16 + ln16;
            float bv = b2f(bias[col]);
            #pragma unroll
            for (int r = 0; r < 4; r++) {
                int row = bm + wmr + mi * 16 + q * 4 + r;
                float v = acc[mi][ni][r] + bv;
                if constexpr (RESID) v += b2f(A[(size_t)row * IC + col]);
                Out[(size_t)row * DWC + col] = f2b(fin(fmaxf(v, 0.0f)));
            }
        }
}

// ------------------------------------------------- MFMA highway (dual GEMM)
__global__ __launch_bounds__(512) void highway_mfma(
    const short* __restrict__ Y, const short* __restrict__ WgT,
    const short* __restrict__ bg, const short* __restrict__ WhT,
    const short* __restrict__ bh, short* __restrict__ Out)
{
    __shared__ __align__(16) short As[128 * 32];
    __shared__ __align__(16) short Bg[128 * 32];
    __shared__ __align__(16) short Bh[128 * 32];
    int bx, by;
    swz(blockIdx.x, gridDim.x, bx, by);
    const int bm = by * 128;
    const int bn = bx * 128;
    const int tid = threadIdx.x;
    const int wave = tid >> 6, lane = tid & 63;
    const int wmr = (wave >> 1) * 32, wnc = (wave & 1) * 64;
    const int q = lane >> 4, ln16 = lane & 15;
    const int sr = tid >> 2, sch = tid & 3, sc = sch * 8;
    const int sw = swidx(sr, sch);

    f4v accg[2][4] = {};
    f4v acch[2][4] = {};
    uint4 ra, rg, rh;

    ra = *(const uint4*)(Y + (size_t)(bm + sr) * DWC + sc);
    rg = *(const uint4*)(WgT + (size_t)(bn + sr) * DWC + sc);
    rh = *(const uint4*)(WhT + (size_t)(bn + sr) * DWC + sc);

    for (int k0 = 0; k0 < DWC; k0 += 32) {
        *(uint4*)(&As[sw]) = ra;
        *(uint4*)(&Bg[sw]) = rg;
        *(uint4*)(&Bh[sw]) = rh;
        __syncthreads();
        if (k0 + 32 < DWC) {
            int kn = k0 + 32;
            ra = *(const uint4*)(Y + (size_t)(bm + sr) * DWC + kn + sc);
            rg = *(const uint4*)(WgT + (size_t)(bn + sr) * DWC + kn + sc);
            rh = *(const uint4*)(WhT + (size_t)(bn + sr) * DWC + kn + sc);
        }
        s8v af[2], bgf[4], bhf[4];
        #pragma unroll
        for (int mi = 0; mi < 2; mi++) af[mi] = *(const s8v*)(&As[swidx(wmr + mi * 16 + ln16, q)]);
        #pragma unroll
        for (int ni = 0; ni < 4; ni++) {
            bgf[ni] = *(const s8v*)(&Bg[swidx(wnc + ni * 16 + ln16, q)]);
            bhf[ni] = *(const s8v*)(&Bh[swidx(wnc + ni * 16 + ln16, q)]);
        }
        #pragma unroll
        for (int mi = 0; mi < 2; mi++)
            #pragma unroll
            for (int ni = 0; ni < 4; ni++) {
                accg[mi][ni] = __builtin_amdgcn_mfma_f32_16x16x32_bf16(
                    af[mi], bgf[ni], accg[mi][ni], 0, 0, 0);
                acch[mi][ni] = __builtin_amdgcn_mfma_f32_16x16x32_bf16(
                    af[mi], bhf[ni], acch[mi][ni], 0, 0, 0);
            }
        __syncthreads();
    }

    #pragma unroll
    for (int mi = 0; mi < 2; mi++)
        #pragma unroll
        for (int ni = 0; ni < 4; ni++) {
            int col = bn + wnc + ni * 16 + ln16;
            float bgv = b2f(bg[col]);
            float bhv = b2f(bh[col]);
            #pragma unroll
            for (int r = 0; r < 4; r++) {
                int row = bm + wmr + mi * 16 + q * 4 + r;
                float g = 1.0f / (1.0f + expf(-(accg[mi][ni][r] + bgv)));
                float h = fmaxf(acch[mi][ni][r] + bhv, 0.0f);
                float y = b2f(Y[(size_t)row * DWC + col]);
                Out[(size_t)row * DWC + col] = f2b(fin(g * h + (1.0f - g) * y));
            }
        }
}

// ------------------------------------------------- MFMA projection
__global__ __launch_bounds__(512) void proj_mfma(
    const short* __restrict__ A, const short* __restrict__ WT,
    const short* __restrict__ bias, const int* __restrict__ flags,
    void* __restrict__ Out, int oroff)
{
    __shared__ __align__(16) short As[128 * 32];
    __shared__ __align__(16) short Bs[128 * 32];
    int bx, by;
    swz(blockIdx.x, gridDim.x, bx, by);
    const int bm = by * 128;
    const int bn = bx * 128;
    const int tid = threadIdx.x;
    const int wave = tid >> 6, lane = tid & 63;
    const int wmr = (wave >> 1) * 32, wnc = (wave & 1) * 64;
    const int q = lane >> 4, ln16 = lane & 15;
    const int sr = tid >> 2, sch = tid & 3, sc = sch * 8;
    const int sw = swidx(sr, sch);
    const int f32 = flags[4];

    f4v acc[2][4] = {};
    uint4 ra, rb;
    ra = *(const uint4*)(A + (size_t)(bm + sr) * DWC + sc);
    rb = *(const uint4*)(WT + (size_t)(bn + sr) * DWC + sc);

    for (int k0 = 0; k0 < DWC; k0 += 32) {
        *(uint4*)(&As[sw]) = ra;
        *(uint4*)(&Bs[sw]) = rb;
        __syncthreads();
        if (k0 + 32 < DWC) {
            int kn = k0 + 32;
            ra = *(const uint4*)(A + (size_t)(bm + sr) * DWC + kn + sc);
            rb = *(const uint4*)(WT + (size_t)(bn + sr) * DWC + kn + sc);
        }
        s8v af[2], bf[4];
        #pragma unroll
        for (int mi = 0; mi < 2; mi++) af[mi] = *(const s8v*)(&As[swidx(wmr + mi * 16 + ln16, q)]);
        #pragma unroll
        for (int ni = 0; ni < 4; ni++) bf[ni] = *(const s8v*)(&Bs[swidx(wnc + ni * 16 + ln16, q)]);
        #pragma unroll
        for (int mi = 0; mi < 2; mi++)
            #pragma unroll
            for (int ni = 0; ni < 4; ni++)
                acc[mi][ni] = __builtin_amdgcn_mfma_f32_16x16x32_bf16(
                    af[mi], bf[ni], acc[mi][ni], 0, 0, 0);
        __syncthreads();
    }

    #pragma unroll
    for (int mi = 0; mi < 2; mi++)
        #pragma unroll
        for (int ni = 0; ni < 4; ni++) {
            int col = bn + wnc + ni * 16 + ln16;
            float bv = b2f(bias[col]);
            #pragma unroll
            for (int r = 0; r < 4; r++) {
                int row = bm + wmr + mi * 16 + q * 4 + r;
                float v = fin(acc[mi][ni][r] + bv);
                size_t oi = (size_t)(oroff + row) * DWC + col;
                if (f32) ((float*)Out)[oi] = v;
                else     ((bf16*)Out)[oi] = __float2bfloat16(v);
            }
        }
}

// ---------------------------------------------------------------- bounds / segmax
__global__ __launch_bounds__(256) void bounds_kernel(
    const int* __restrict__ seg, const int* __restrict__ flags,
    int* __restrict__ wstart, int* __restrict__ wend, int bt0)
{
    int il = blockIdx.x * 256 + threadIdx.x;
    int ig = bt0 + il;
    int is64 = flags[3];
    const long long* seg64 = (const long long*)seg;
    int t = il & (T_SEQ - 1);
    int bl = il >> 12;
    int s  = (is64 ? (int)seg64[ig] : seg[ig]) & 1023;
    int sp = (t == 0)         ? -1 : ((is64 ? (int)seg64[ig - 1] : seg[ig - 1]) & 1023);
    int sn = (t == T_SEQ - 1) ? -1 : ((is64 ? (int)seg64[ig + 1] : seg[ig + 1]) & 1023);
    int bw = (bl << 10) + s;
    if (sp != s) wstart[bw] = t;
    if (sn != s) wend[bw] = t;
}

__global__ __launch_bounds__(512) void segmax_kernel(
    const short* __restrict__ Y, const int* __restrict__ wstart,
    const int* __restrict__ wend, short* __restrict__ Out)
{
    int bw = blockIdx.x;
    int d = threadIdx.x;
    int bl = bw >> 10;
    int s = wstart[bw], e = wend[bw];
    s = min(max(s, 0), T_SEQ - 1);
    e = min(max(e, s), T_SEQ - 1);
    float m = b2f(Y[(size_t)((bl << 12) + s) * DWC + d]);
    for (int t = s + 1; t <= e; ++t)
        m = fmaxf(m, b2f(Y[(size_t)((bl << 12) + t) * DWC + d]));
    Out[(size_t)bw * DWC + d] = f2b(fin(m));
}

// ---------------------------------------------------------------- launch
extern "C" void kernel_launch(void* const* d_in, const int* in_sizes, int n_in,
                              void* d_out, int out_size, void* d_ws, size_t ws_size,
                              hipStream_t stream)
{
    static const int expect[19] = {32768, 32768, 32768, 32768, 16896,
                                   98304, 512, 524288, 1024, 524288, 1024,
                                   786432, 512, 524288, 1024, 524288, 1024,
                                   262144, 512};
    int bad = -1;
    if (n_in < 19) bad = 31;
    else for (int i = 0; i < 19; i++) if (in_sizes[i] != expect[i]) { bad = i; break; }
    if (bad >= 0) {
        diag_kernel<<<dim3((out_size + 255) / 256), dim3(256), 0, stream>>>(
            (bf16*)d_out, out_size, 1e35f * (float)(1 + bad));
        return;
    }

    char* ws = (char*)d_ws;
    const size_t WBREG = 8ull << 20;
    short* WB    = (short*)ws;
    int*   flags = (int*)(ws + 6500352);
    const size_t perC = 8921088 + 8192 + 64;
    int C = 8;
    while (C > 1 && WBREG + (size_t)C * perC > ws_size) C >>= 1;
    if (WBREG + (size_t)C * perC > ws_size) {
        float ws_mib = (float)((double)ws_size / 1048576.0);
        diag_kernel<<<dim3((out_size + 255) / 256), dim3(256), 0, stream>>>(
            (bf16*)d_out, out_size, 1e30f * (16.0f + ws_mib));
        return;
    }

    const int*  byte_tokens = (const int*)d_in[0];
    const unsigned char* bpe_mask = (const unsigned char*)d_in[1];
    const unsigned char* word_mask = (const unsigned char*)d_in[2];
    const int*  seg_ids     = (const int*)d_in[3];
    const void* tok_emb = d_in[4];

    detect_kernel<<<dim3(1), dim3(256), 0, stream>>>(
        byte_tokens, bpe_mask, word_mask, seg_ids,
        (const unsigned int*)tok_emb, flags);

    convert_weights<<<dim3((WB_TOTAL + 255) / 256), dim3(256), 0, stream>>>(
        d_in[5], d_in[6], d_in[7], d_in[8], d_in[9], d_in[10],
        d_in[11], d_in[12], d_in[13], d_in[14], d_in[15], d_in[16],
        d_in[17], d_in[18], flags, WB);

    short* c0wT = WB;            short* c0b  = WB + 98304;
    short* h0gT = WB + 98816;    short* h0bg = WB + 623104;
    short* h0hT = WB + 624128;   short* h0bh = WB + 1148416;
    short* c1wT = WB + 1149440;  short* c1b  = WB + 1935872;
    short* h1gT = WB + 1936384;  short* h1bg = WB + 2460672;
    short* h1hT = WB + 2461696;  short* h1bh = WB + 2985984;
    short* pwT  = WB + 2987008;  short* pb   = WB + 3249152;
    const int LOFF = 262144, LBOFF = 512;

    for (int b0 = 0; b0 < 8; b0 += C) {
        const int rows  = C * T_SEQ;
        const int words = C * 1024;
        char*  chunk  = ws + WBREG;
        short* xe     = (short*)chunk;
        short* U      = (short*)(chunk + (size_t)C * 524288);
        short* V      = (short*)(chunk + (size_t)C * (524288 + 4194304));
        int*   wstart = (int*)(chunk + (size_t)C * 8912896);
        int*   wend   = wstart + words;
        short* segout = U;

        embed_kernel<<<dim3(rows * 64 / 256), dim3(256), 0, stream>>>(
            byte_tokens, bpe_mask, word_mask, tok_emb, flags, xe, b0 * T_SEQ);

        dim3 gg(4 * (rows / 128));   // 1D swizzled grid
        conv_mfma<64, false><<<gg, dim3(512), 0, stream>>>(xe, c0wT, c0b, U);

        highway_mfma<<<gg, dim3(512), 0, stream>>>(U, h0gT, h0bg, h0hT, h0bh, V);
        highway_mfma<<<gg, dim3(512), 0, stream>>>(V, h0gT + LOFF, h0bg + LBOFF,
                                                   h0hT + LOFF, h0bh + LBOFF, U);

        conv_mfma<512, true><<<gg, dim3(512), 0, stream>>>(U, c1wT, c1b, V);

        highway_mfma<<<gg, dim3(512), 0, stream>>>(V, h1gT, h1bg, h1hT, h1bh, U);
        highway_mfma<<<gg, dim3(512), 0, stream>>>(U, h1gT + LOFF, h1bg + LBOFF,
                                                   h1hT + LOFF, h1bh + LBOFF, V);

        bounds_kernel<<<dim3(rows / 256), dim3(256), 0, stream>>>(
            seg_ids, flags, wstart, wend, b0 * T_SEQ);

        segmax_kernel<<<dim3(words), dim3(512), 0, stream>>>(V, wstart, wend, segout);

        proj_mfma<<<dim3(4 * (words / 128)), dim3(512), 0, stream>>>(
            segout, pwT, pb, flags, d_out, b0 * 1024);
    }
}